// Round 1
// baseline (1522.147 us; speedup 1.0000x reference)
//
#include <hip/hip_runtime.h>

typedef unsigned short u16;
typedef __attribute__((ext_vector_type(8))) short short8;
typedef __attribute__((ext_vector_type(4))) float f32x4;

#define FLAG_BIAS 1
#define FLAG_TANH 2
#define FLAG_MASK 4
#define FLAG_BF16 8

__device__ __forceinline__ float fast_tanh(float x) {
  // exact: tanh(x) = 1 - 2/(e^{2x}+1); saturates correctly for |x| large
  return 1.f - 2.f / (__expf(2.f * x) + 1.f);
}

__device__ __forceinline__ u16 f2bf(float f) {
  unsigned u = __float_as_uint(f);
  return (u16)((u + 0x7fffu + ((u >> 16) & 1u)) >> 16); // RNE
}

__device__ __forceinline__ void gload_lds16(const void* g, void* l) {
  __builtin_amdgcn_global_load_lds(
      (const __attribute__((address_space(1))) unsigned int*)g,
      (__attribute__((address_space(3))) unsigned int*)l, 16, 0, 0);
}

// ---------------------------------------------------------------------------
// Generic NT GEMM: Out[r][c] = sum_k X[r][k] * Y[c][k]   (both K-contiguous)
// 128x128 tile, BK=32, 4 waves of 64x64, mfma_f32_16x16x32_bf16.
// ---------------------------------------------------------------------------
__global__ __launch_bounds__(256)
void gemm_nt(const u16* __restrict__ X, long long xbs, int ldx,
             const u16* __restrict__ Y, long long ybs, int ldy,
             void* __restrict__ Outv, long long obs, int ldo,
             int K, int flags,
             const float* __restrict__ bias,
             const int* __restrict__ rmask, int rms,
             const int* __restrict__ cmask, int cms) {
  __shared__ u16 lx[128][32];
  __shared__ u16 ly[128][32];
  const int t = threadIdx.x;
  const int lane = t & 63, wid = t >> 6;
  const int wr = (wid >> 1) * 64, wc = (wid & 1) * 64;
  const int bz = blockIdx.z;
  const u16* Xb = X + (size_t)bz * xbs + (size_t)blockIdx.y * 128 * ldx;
  const u16* Yb = Y + (size_t)bz * ybs + (size_t)blockIdx.x * 128 * ldy;
  const int srow = t >> 2, scol = (t & 3) * 8;
  char* lxB = (char*)&lx[0][0];
  char* lyB = (char*)&ly[0][0];

  f32x4 acc[4][4];
#pragma unroll
  for (int m = 0; m < 4; m++)
#pragma unroll
    for (int n = 0; n < 4; n++) acc[m][n] = (f32x4){0.f, 0.f, 0.f, 0.f};

  for (int kk = 0; kk < K; kk += 32) {
    if (kk) __syncthreads();
#pragma unroll
    for (int j = 0; j < 2; j++) {
      gload_lds16(Xb + (size_t)(j * 64 + srow) * ldx + kk + scol, lxB + j * 4096 + t * 16);
      gload_lds16(Yb + (size_t)(j * 64 + srow) * ldy + kk + scol, lyB + j * 4096 + t * 16);
    }
    __syncthreads();
    short8 av[4], bv[4];
    const int r16 = lane & 15, kh = (lane >> 4) * 8;
#pragma unroll
    for (int m = 0; m < 4; m++) av[m] = *(const short8*)&lx[wr + m * 16 + r16][kh];
#pragma unroll
    for (int n = 0; n < 4; n++) bv[n] = *(const short8*)&ly[wc + n * 16 + r16][kh];
#pragma unroll
    for (int m = 0; m < 4; m++)
#pragma unroll
      for (int n = 0; n < 4; n++)
        acc[m][n] = __builtin_amdgcn_mfma_f32_16x16x32_bf16(av[m], bv[n], acc[m][n], 0, 0, 0);
  }

  // epilogue: C/D layout col = lane&15, row = (lane>>4)*4 + j  [m89-verified]
  const int rowbase = blockIdx.y * 128 + wr + ((lane >> 4) << 2);
  const int colbase = blockIdx.x * 128 + wc + (lane & 15);
#pragma unroll
  for (int m = 0; m < 4; m++) {
#pragma unroll
    for (int n = 0; n < 4; n++) {
      const int c = colbase + n * 16;
      const float bcol = (flags & FLAG_BIAS) ? bias[c] : 0.f;
      const float cmv = (flags & FLAG_MASK) ? (float)cmask[(size_t)bz * cms + c] : 1.f;
#pragma unroll
      for (int j = 0; j < 4; j++) {
        const int r = rowbase + m * 16 + j;
        float v = acc[m][n][j] + bcol;
        if (flags & FLAG_TANH) v = fast_tanh(v);
        if (flags & FLAG_MASK) v *= cmv * (float)rmask[(size_t)bz * rms + r];
        const size_t oi = (size_t)bz * obs + (size_t)r * ldo + c;
        if (flags & FLAG_BF16) ((u16*)Outv)[oi] = f2bf(v);
        else ((float*)Outv)[oi] = v;
      }
    }
  }
}

// ---------------------------------------------------------------------------
// bf16 [R][C] -> [C][R] per batch (z)
// ---------------------------------------------------------------------------
__global__ void transpose_bf16(const u16* __restrict__ in, u16* __restrict__ out, int R, int C) {
  __shared__ u16 tl[32][33];
  const size_t bo = (size_t)blockIdx.z * R * C;
  const int c0 = blockIdx.x * 32, r0 = blockIdx.y * 32;
  for (int i = threadIdx.y; i < 32; i += 8)
    tl[i][threadIdx.x] = in[bo + (size_t)(r0 + i) * C + c0 + threadIdx.x];
  __syncthreads();
  for (int i = threadIdx.y; i < 32; i += 8)
    out[bo + (size_t)(c0 + i) * R + r0 + threadIdx.x] = tl[threadIdx.x][i];
}

// f32 [256][256] -> bf16 [256][256] transposed, per matrix (z)
__global__ void wtrans(const float* __restrict__ in, u16* __restrict__ out) {
  __shared__ float tl[32][33];
  const size_t bo = (size_t)blockIdx.z * 256 * 256;
  const int c0 = blockIdx.x * 32, r0 = blockIdx.y * 32;
  for (int i = threadIdx.y; i < 32; i += 8)
    tl[i][threadIdx.x] = in[bo + (size_t)(r0 + i) * 256 + c0 + threadIdx.x];
  __syncthreads();
  for (int i = threadIdx.y; i < 32; i += 8)
    out[bo + (size_t)(c0 + i) * 256 + r0 + threadIdx.x] = f2bf(tl[threadIdx.x][i]);
}

__global__ void conv_bf16(const float* __restrict__ in, u16* __restrict__ out, int n4) {
  const int i = blockIdx.x * 256 + threadIdx.x;
  if (i >= n4) return;
  const float4 v = ((const float4*)in)[i];
  ushort4 o;
  o.x = f2bf(v.x); o.y = f2bf(v.y); o.z = f2bf(v.z); o.w = f2bf(v.w);
  ((ushort4*)out)[i] = o;
}

// one wave per token: score = dot(comb[tok, 0:512], wvec) + bias
__global__ void scores_kernel(const float* __restrict__ comb, int tokstride,
                              const float* __restrict__ wvec, const float* __restrict__ bsc,
                              float* __restrict__ outp) {
  const int lane = threadIdx.x & 63, wid = threadIdx.x >> 6;
  const int tok = blockIdx.x * 4 + wid;
  const float* p = comb + (size_t)tok * tokstride + lane * 8;
  const float4 a = *(const float4*)p, b = *(const float4*)(p + 4);
  const float* wp = wvec + lane * 8;
  const float4 wa = *(const float4*)wp, wb = *(const float4*)(wp + 4);
  float s = a.x * wa.x + a.y * wa.y + a.z * wa.z + a.w * wa.w +
            b.x * wb.x + b.y * wb.y + b.z * wb.z + b.w * wb.w;
#pragma unroll
  for (int off = 32; off; off >>= 1) s += __shfl_down(s, off);
  if (lane == 0) outp[tok] = s + bsc[0];
}

// per-b masked softmax over ntok scores + weighted pooling of feat -> pool[b][*]
__global__ __launch_bounds__(256)
void pool_kernel(const float* __restrict__ scores, const int* __restrict__ mask,
                 const float* __restrict__ feat, float* __restrict__ pool,
                 int ntok, int poolld) {
  const int b = blockIdx.x, t = threadIdx.x;
  const float* s = scores + (size_t)b * ntok;
  const int* mk = mask + (size_t)b * ntok;
  __shared__ float red[256];
  __shared__ float w[2048];
  float m = -1e30f;
  for (int i = t; i < ntok; i += 256) m = fmaxf(m, s[i]);
  red[t] = m;
  __syncthreads();
  for (int h = 128; h; h >>= 1) { if (t < h) red[t] = fmaxf(red[t], red[t + h]); __syncthreads(); }
  const float smax = red[0];
  __syncthreads();
  float sum = 0.f;
  for (int i = t; i < ntok; i += 256) {
    const float e = __expf(s[i] - smax) * (float)mk[i];
    w[i] = e;
    sum += e;
  }
  red[t] = sum;
  __syncthreads();
  for (int h = 128; h; h >>= 1) { if (t < h) red[t] += red[t + h]; __syncthreads(); }
  const float inv = 1.f / (red[0] + 1e-6f);
  float a0 = 0.f, a1 = 0.f, a2 = 0.f, a3 = 0.f;
  const float* fb = feat + (size_t)b * ntok * 256 + t;
  for (int i = 0; i < ntok; i += 4) {
    a0 += w[i]     * fb[(size_t)i * 256];
    a1 += w[i + 1] * fb[(size_t)(i + 1) * 256];
    a2 += w[i + 2] * fb[(size_t)(i + 2) * 256];
    a3 += w[i + 3] * fb[(size_t)(i + 3) * 256];
  }
  pool[(size_t)b * poolld + t] = (a0 + a1 + a2 + a3) * inv;
}

// out[b][n] = bias[n] + sum_k pool[b][k] * W[k][n]   (K=1024, N=256)
__global__ void final_kernel(const float* __restrict__ pool, const float* __restrict__ W,
                             const float* __restrict__ bias, float* __restrict__ outp) {
  const int b = blockIdx.x, n = threadIdx.x, q = threadIdx.y;
  __shared__ float red[4][256];
  float acc = 0.f;
  const float* p = pool + b * 1024 + q * 256;
  const float* w = W + (size_t)q * 256 * 256;
  for (int k = 0; k < 256; k++) acc += p[k] * w[(size_t)k * 256 + n];
  red[q][n] = acc;
  __syncthreads();
  if (q == 0) outp[b * 256 + n] = red[0][n] + red[1][n] + red[2][n] + red[3][n] + bias[n];
}

// ---------------------------------------------------------------------------
static inline void launch_gemm(hipStream_t s, const u16* X, long long xbs, int ldx,
                               const u16* Y, long long ybs, int ldy,
                               void* Out, long long obs, int ldo,
                               int M, int N, int K, int nb, int flags,
                               const float* bias, const int* rm, int rms,
                               const int* cm, int cms) {
  dim3 g(N / 128, M / 128, nb);
  gemm_nt<<<g, dim3(256), 0, s>>>(X, xbs, ldx, Y, ybs, ldy, Out, obs, ldo, K, flags,
                                  bias, rm, rms, cm, cms);
}

extern "C" void kernel_launch(void* const* d_in, const int* in_sizes, int n_in,
                              void* d_out, int out_size, void* d_ws, size_t ws_size,
                              hipStream_t stream) {
  (void)in_sizes; (void)n_in; (void)out_size; (void)ws_size;
  enum { Bc = 16, LCc = 512, LPc = 2048, Dc = 256, Lc = 4 };

  const float* comp_feat = (const float*)d_in[0];
  const int*   comp_mask = (const int*)d_in[1];
  const float* prot_feat = (const float*)d_in[2];
  const int*   prot_mask = (const int*)d_in[3];
  const float* U     = (const float*)d_in[4];
  const float* W_p2c = (const float*)d_in[5];
  const float* b_p2c = (const float*)d_in[6];
  const float* W_c2p = (const float*)d_in[7];
  const float* b_c2p = (const float*)d_in[8];
  const float* W_hc  = (const float*)d_in[9];
  const float* b_hc  = (const float*)d_in[10];
  const float* W_hp  = (const float*)d_in[11];
  const float* b_hp  = (const float*)d_in[12];
  const float* W_ac  = (const float*)d_in[13];
  const float* b_ac  = (const float*)d_in[14];
  const float* W_ap  = (const float*)d_in[15];
  const float* b_ap  = (const float*)d_in[16];
  const float* W_cc  = (const float*)d_in[17];
  const float* b_cc  = (const float*)d_in[18];
  const float* W_cp  = (const float*)d_in[19];
  const float* b_cp  = (const float*)d_in[20];

  float* out_cf = (float*)d_out;                       // [16][256]
  float* out_pf = out_cf + Bc * Dc;                    // [16][256]
  float* CLW = out_pf + Bc * Dc;                       // [16][512][2048]
  float* PLW = CLW + (size_t)Bc * LCc * 2 * Dc * Lc;   // [16][2048][2048]

  char* wsp = (char*)d_ws;
  size_t off = 0;
  auto carve = [&](size_t bytes) -> char* {
    char* p = wsp + off;
    off += (bytes + 255) & ~(size_t)255;
    return p;
  };
  u16* cfb    = (u16*)carve((size_t)Bc * LCc * Dc * 2);
  u16* pfb    = (u16*)carve((size_t)Bc * LPc * Dc * 2);
  u16* Utb    = (u16*)carve((size_t)Lc * Dc * Dc * 2);
  u16* Wp2ct  = (u16*)carve((size_t)Lc * Dc * Dc * 2);
  u16* Wc2pt  = (u16*)carve((size_t)Lc * Dc * Dc * 2);
  u16* Whct   = (u16*)carve((size_t)Lc * Dc * Dc * 2);
  u16* Whpt   = (u16*)carve((size_t)Lc * Dc * Dc * 2);
  u16* CUb    = (u16*)carve((size_t)Bc * LCc * Dc * 2);
  u16* C2Pb   = (u16*)carve((size_t)Bc * LCc * Dc * 2);
  u16* C2Ptb  = (u16*)carve((size_t)Bc * LCc * Dc * 2);
  u16* P2Cb   = (u16*)carve((size_t)Bc * LPc * Dc * 2);
  u16* P2Ctb  = (u16*)carve((size_t)Bc * LPc * Dc * 2);
  u16* Ab     = (u16*)carve((size_t)Bc * LCc * LPc * 2);
  u16* Atb    = (u16*)carve((size_t)Bc * LCc * LPc * 2);
  float* scoresC = (float*)carve((size_t)Bc * LCc * 4);
  float* scoresP = (float*)carve((size_t)Bc * LPc * 4);
  float* poolc   = (float*)carve((size_t)Bc * Lc * Dc * 4);
  float* poolp   = (float*)carve((size_t)Bc * Lc * Dc * 4);

  // --- init: bf16 copies of features, transposed bf16 weights ---
  conv_bf16<<<dim3(Bc * LCc * Dc / 4 / 256), dim3(256), 0, stream>>>(comp_feat, cfb, Bc * LCc * Dc / 4);
  conv_bf16<<<dim3(Bc * LPc * Dc / 4 / 256), dim3(256), 0, stream>>>(prot_feat, pfb, Bc * LPc * Dc / 4);
  {
    dim3 wg(8, 8, Lc), wb(32, 8);
    wtrans<<<wg, wb, 0, stream>>>(U, Utb);
    wtrans<<<wg, wb, 0, stream>>>(W_p2c, Wp2ct);
    wtrans<<<wg, wb, 0, stream>>>(W_c2p, Wc2pt);
    wtrans<<<wg, wb, 0, stream>>>(W_hc, Whct);
    wtrans<<<wg, wb, 0, stream>>>(W_hp, Whpt);
  }

  const int LW = 2 * Dc * Lc;  // 2048, layerwise row stride

  for (int i = 0; i < Lc; i++) {
    const size_t wo = (size_t)i * Dc * Dc;
    // small GEMMs (batch merged into M)
    launch_gemm(stream, cfb, 0, Dc, Utb + wo, 0, Dc, CUb, 0, Dc,
                Bc * LCc, Dc, Dc, 1, FLAG_BF16, nullptr, nullptr, 0, nullptr, 0);
    launch_gemm(stream, cfb, 0, Dc, Wc2pt + wo, 0, Dc, C2Pb, 0, Dc,
                Bc * LCc, Dc, Dc, 1, FLAG_BIAS | FLAG_TANH | FLAG_BF16, b_c2p + i * Dc,
                nullptr, 0, nullptr, 0);
    launch_gemm(stream, pfb, 0, Dc, Wp2ct + wo, 0, Dc, P2Cb, 0, Dc,
                Bc * LPc, Dc, Dc, 1, FLAG_BIAS | FLAG_TANH | FLAG_BF16, b_p2c + i * Dc,
                nullptr, 0, nullptr, 0);
    launch_gemm(stream, cfb, 0, Dc, Whct + wo, 0, Dc, CLW + i * 2 * Dc, 0, LW,
                Bc * LCc, Dc, Dc, 1, FLAG_BIAS | FLAG_TANH, b_hc + i * Dc,
                nullptr, 0, nullptr, 0);
    launch_gemm(stream, pfb, 0, Dc, Whpt + wo, 0, Dc, PLW + i * 2 * Dc, 0, LW,
                Bc * LPc, Dc, Dc, 1, FLAG_BIAS | FLAG_TANH, b_hp + i * Dc,
                nullptr, 0, nullptr, 0);
    // transposes for NT layout
    transpose_bf16<<<dim3(Dc / 32, LPc / 32, Bc), dim3(32, 8), 0, stream>>>(P2Cb, P2Ctb, LPc, Dc);
    transpose_bf16<<<dim3(Dc / 32, LCc / 32, Bc), dim3(32, 8), 0, stream>>>(C2Pb, C2Ptb, LCc, Dc);
    // GEMM-1: A = tanh(CU · pf^T) * mask   [b: 512 x 2048, K=256]
    launch_gemm(stream, CUb, (long long)LCc * Dc, Dc, pfb, (long long)LPc * Dc, Dc,
                Ab, (long long)LCc * LPc, LPc, LCc, LPc, Dc, Bc,
                FLAG_TANH | FLAG_MASK | FLAG_BF16, nullptr, comp_mask, LCc, prot_mask, LPc);
    transpose_bf16<<<dim3(LPc / 32, LCc / 32, Bc), dim3(32, 8), 0, stream>>>(Ab, Atb, LCc, LPc);
    // GEMM-2: comp_cross = A · P2C     [b: 512 x 256, K=2048] -> CLW[..., i*512+256:]
    launch_gemm(stream, Ab, (long long)LCc * LPc, LPc, P2Ctb, (long long)Dc * LPc, LPc,
                CLW + i * 2 * Dc + Dc, (long long)LCc * LW, LW, LCc, Dc, LPc, Bc,
                0, nullptr, nullptr, 0, nullptr, 0);
    // GEMM-3: prot_cross = A^T · C2P   [b: 2048 x 256, K=512] -> PLW[..., i*512+256:]
    launch_gemm(stream, Atb, (long long)LCc * LPc, LCc, C2Ptb, (long long)Dc * LCc, LCc,
                PLW + i * 2 * Dc + Dc, (long long)LPc * LW, LW, LPc, Dc, LCc, Bc,
                0, nullptr, nullptr, 0, nullptr, 0);
    // attention scores + masked-softmax pooling
    scores_kernel<<<dim3(Bc * LCc / 4), dim3(256), 0, stream>>>(CLW + i * 2 * Dc, LW,
                                                                W_ac + i * 2 * Dc, b_ac + i, scoresC);
    scores_kernel<<<dim3(Bc * LPc / 4), dim3(256), 0, stream>>>(PLW + i * 2 * Dc, LW,
                                                                W_ap + i * 2 * Dc, b_ap + i, scoresP);
    pool_kernel<<<dim3(Bc), dim3(256), 0, stream>>>(scoresC, comp_mask, comp_feat,
                                                    poolc + i * Dc, LCc, Lc * Dc);
    pool_kernel<<<dim3(Bc), dim3(256), 0, stream>>>(scoresP, prot_mask, prot_feat,
                                                    poolp + i * Dc, LPc, Lc * Dc);
  }

  final_kernel<<<dim3(Bc), dim3(256, 4), 0, stream>>>(poolc, W_cc, b_cc, out_cf);
  final_kernel<<<dim3(Bc), dim3(256, 4), 0, stream>>>(poolp, W_cp, b_cp, out_pf);
}

// Round 2
// 882.338 us; speedup vs baseline: 1.7251x; 1.7251x over previous
//
#include <hip/hip_runtime.h>

typedef unsigned short u16;
typedef __attribute__((ext_vector_type(8))) short short8;
typedef __attribute__((ext_vector_type(4))) float f32x4;

#define FLAG_BIAS   1
#define FLAG_TANH   2
#define FLAG_MASK   4
#define FLAG_BF16   8
#define FLAG_NSTORE 16
#define FLAG_TSTORE 32
#define FLAG_SPLITN 64

__device__ __forceinline__ float fast_tanh(float x) {
  return 1.f - 2.f / (__expf(2.f * x) + 1.f);
}

__device__ __forceinline__ u16 f2bf(float f) {
  unsigned u = __float_as_uint(f);
  return (u16)((u + 0x7fffu + ((u >> 16) & 1u)) >> 16); // RNE
}

__device__ __forceinline__ void gload_lds16(const void* g, void* l) {
  __builtin_amdgcn_global_load_lds(
      (const __attribute__((address_space(1))) unsigned int*)g,
      (__attribute__((address_space(3))) unsigned int*)l, 16, 0, 0);
}

// ---------------------------------------------------------------------------
// Generic NT GEMM: Out[r][c] = sum_k X[r][k] * Y[c][k]   (both K-contiguous)
// 128x128 tile, BK=32, 4 waves of 64x64, mfma_f32_16x16x32_bf16.
// Epilogue: LDS-bounce coalesced stores; optional transposed bf16 store.
// ---------------------------------------------------------------------------
__global__ __launch_bounds__(256)
void gemm_nt(const u16* __restrict__ X, long long xbs, int ldx,
             const u16* __restrict__ Y, long long ybs, int ldy,
             void* __restrict__ Outv, long long obs, int ldo,
             u16* __restrict__ Tout, long long tobs, int tldo,
             int K, int flags,
             const float* __restrict__ bias,
             const int* __restrict__ rmask, int rms,
             const int* __restrict__ cmask, int cms) {
  __shared__ __align__(16) char smem[17408];
  u16* lxB = (u16*)smem;                 // [128][32]
  u16* lyB = (u16*)(smem + 8192);        // [128][32]
  const int t = threadIdx.x;
  const int lane = t & 63, wid = t >> 6;
  const int wr = (wid >> 1) * 64, wc = (wid & 1) * 64;
  const int bz = blockIdx.z;
  const int rb = blockIdx.y * 128;   // row tile base
  const int cb = blockIdx.x * 128;   // col tile base
  const u16* Xb = X + (size_t)bz * xbs + (size_t)rb * ldx;
  const u16* Yb = Y + (size_t)bz * ybs + (size_t)cb * ldy;
  const int srow = t >> 2, scol = (t & 3) * 8;

  f32x4 acc[4][4];
#pragma unroll
  for (int m = 0; m < 4; m++)
#pragma unroll
    for (int n = 0; n < 4; n++) acc[m][n] = (f32x4){0.f, 0.f, 0.f, 0.f};

  for (int kk = 0; kk < K; kk += 32) {
    if (kk) __syncthreads();
#pragma unroll
    for (int j = 0; j < 2; j++) {
      gload_lds16(Xb + (size_t)(j * 64 + srow) * ldx + kk + scol, (char*)lxB + j * 4096 + t * 16);
      gload_lds16(Yb + (size_t)(j * 64 + srow) * ldy + kk + scol, (char*)lyB + j * 4096 + t * 16);
    }
    __syncthreads();
    short8 av[4], bv[4];
    const int r16 = lane & 15, kh = (lane >> 4) * 8;
#pragma unroll
    for (int m = 0; m < 4; m++) av[m] = *(const short8*)&lxB[(wr + m * 16 + r16) * 32 + kh];
#pragma unroll
    for (int n = 0; n < 4; n++) bv[n] = *(const short8*)&lyB[(wc + n * 16 + r16) * 32 + kh];
#pragma unroll
    for (int m = 0; m < 4; m++)
#pragma unroll
      for (int n = 0; n < 4; n++)
        acc[m][n] = __builtin_amdgcn_mfma_f32_16x16x32_bf16(av[m], bv[n], acc[m][n], 0, 0, 0);
  }

  // --- register-stage epilogue math (bias / tanh / mask) ---
  // value(m,n,j): row = rb + wr + m*16 + (lane>>4)*4 + j, col = cb + wc + n*16 + (lane&15)
  if (flags & (FLAG_BIAS | FLAG_TANH | FLAG_MASK)) {
#pragma unroll
    for (int n = 0; n < 4; n++) {
      const int c = cb + wc + n * 16 + (lane & 15);
      const float bcol = (flags & FLAG_BIAS) ? bias[c] : 0.f;
      const float cmv = (flags & FLAG_MASK) ? (float)cmask[(size_t)bz * cms + c] : 1.f;
#pragma unroll
      for (int m = 0; m < 4; m++) {
#pragma unroll
        for (int j = 0; j < 4; j++) {
          float v = acc[m][n][j] + bcol;
          if (flags & FLAG_TANH) v = fast_tanh(v);
          if (flags & FLAG_MASK) {
            const int r = rb + wr + m * 16 + ((lane >> 4) << 2) + j;
            v *= cmv * (float)rmask[(size_t)bz * rms + r];
          }
          acc[m][n][j] = v;
        }
      }
    }
  }

  const int strip_r = wid >> 1, strip_c = wid & 1;
  const int ocb = (flags & FLAG_SPLITN) ? ((cb >> 8) * 512 + (cb & 255)) : cb;

  if (flags & FLAG_NSTORE) {
#pragma unroll
    for (int m = 0; m < 4; m++) {
      __syncthreads();
      if (flags & FLAG_BF16) {
        u16* bb = (u16*)smem;  // [32][136]
#pragma unroll
        for (int n = 0; n < 4; n++)
#pragma unroll
          for (int j = 0; j < 4; j++)
            bb[(strip_r * 16 + ((lane >> 4) << 2) + j) * 136 + strip_c * 64 + n * 16 + (lane & 15)] =
                f2bf(acc[m][n][j]);
        __syncthreads();
        const int lr = t >> 3, c0 = (t & 7) * 16;
        const int g = rb + (lr >> 4) * 64 + m * 16 + (lr & 15);
        u16* op = (u16*)Outv + (size_t)bz * obs + (size_t)g * ldo + ocb + c0;
#pragma unroll
        for (int q = 0; q < 2; q++)
          ((uint4*)op)[q] = ((const uint4*)&bb[lr * 136 + c0])[q];
      } else {
        float* bb = (float*)smem;  // [32][132]
#pragma unroll
        for (int n = 0; n < 4; n++)
#pragma unroll
          for (int j = 0; j < 4; j++)
            bb[(strip_r * 16 + ((lane >> 4) << 2) + j) * 132 + strip_c * 64 + n * 16 + (lane & 15)] =
                acc[m][n][j];
        __syncthreads();
        const int lr = t >> 3, c0 = (t & 7) * 16;
        const int g = rb + (lr >> 4) * 64 + m * 16 + (lr & 15);
        float* op = (float*)Outv + (size_t)bz * obs + (size_t)g * ldo + ocb + c0;
#pragma unroll
        for (int q = 0; q < 4; q++)
          ((float4*)op)[q] = ((const float4*)&bb[lr * 132 + c0])[q];
      }
    }
  }

  if (flags & FLAG_TSTORE) {
#pragma unroll
    for (int n = 0; n < 4; n++) {
      __syncthreads();
      u16* bb = (u16*)smem;  // [32][136]
#pragma unroll
      for (int m = 0; m < 4; m++)
#pragma unroll
        for (int j = 0; j < 4; j++)
          bb[(strip_c * 16 + (lane & 15)) * 136 + strip_r * 64 + m * 16 + ((lane >> 4) << 2) + j] =
              f2bf(acc[m][n][j]);
      __syncthreads();
      const int lp = t >> 3, r0 = (t & 7) * 16;
      const int cg = cb + (lp >> 4) * 64 + n * 16 + (lp & 15);
      u16* op = Tout + (size_t)bz * tobs + (size_t)cg * tldo + rb + r0;
#pragma unroll
      for (int q = 0; q < 2; q++)
        ((uint4*)op)[q] = ((const uint4*)&bb[lp * 136 + r0])[q];
    }
  }
}

// f32 [256][256] -> bf16 transposed, per matrix (z)
__global__ void wtrans(const float* __restrict__ in, u16* __restrict__ out) {
  __shared__ float tl[32][33];
  const size_t bo = (size_t)blockIdx.z * 256 * 256;
  const int c0 = blockIdx.x * 32, r0 = blockIdx.y * 32;
  for (int i = threadIdx.y; i < 32; i += 8)
    tl[i][threadIdx.x] = in[bo + (size_t)(r0 + i) * 256 + c0 + threadIdx.x];
  __syncthreads();
  for (int i = threadIdx.y; i < 32; i += 8)
    out[bo + (size_t)(c0 + i) * 256 + r0 + threadIdx.x] = f2bf(tl[threadIdx.x][i]);
}

__global__ void conv_bf16(const float* __restrict__ in, u16* __restrict__ out, int n4) {
  const int i = blockIdx.x * 256 + threadIdx.x;
  if (i >= n4) return;
  const float4 v = ((const float4*)in)[i];
  ushort4 o;
  o.x = f2bf(v.x); o.y = f2bf(v.y); o.z = f2bf(v.z); o.w = f2bf(v.w);
  ((ushort4*)out)[i] = o;
}

// one wave per token: score = dot(comb[tok, 0:512], wvec) + bias
__global__ void scores_kernel(const float* __restrict__ comb, int tokstride,
                              const float* __restrict__ wvec, const float* __restrict__ bsc,
                              float* __restrict__ outp) {
  const int lane = threadIdx.x & 63, wid = threadIdx.x >> 6;
  const int tok = blockIdx.x * 4 + wid;
  const float* p = comb + (size_t)tok * tokstride + lane * 8;
  const float4 a = *(const float4*)p, b = *(const float4*)(p + 4);
  const float* wp = wvec + lane * 8;
  const float4 wa = *(const float4*)wp, wb = *(const float4*)(wp + 4);
  float s = a.x * wa.x + a.y * wa.y + a.z * wa.z + a.w * wa.w +
            b.x * wb.x + b.y * wb.y + b.z * wb.z + b.w * wb.w;
#pragma unroll
  for (int off = 32; off; off >>= 1) s += __shfl_down(s, off);
  if (lane == 0) outp[tok] = s + bsc[0];
}

// masked softmax -> normalized weights. grid(64, 2): x = l*16+b, y: 0=comp 1=prot
__global__ __launch_bounds__(256)
void softmax_w(const float* __restrict__ sC, const float* __restrict__ sP,
               const int* __restrict__ cmask, const int* __restrict__ pmask,
               float* __restrict__ wC, float* __restrict__ wP) {
  const int l = blockIdx.x >> 4, b = blockIdx.x & 15, t = threadIdx.x;
  const int ntok = blockIdx.y ? 2048 : 512;
  const float* s = blockIdx.y ? (sP + l * 32768 + b * 2048) : (sC + l * 8192 + b * 512);
  const int* mk = blockIdx.y ? (pmask + b * 2048) : (cmask + b * 512);
  float* w = blockIdx.y ? (wP + l * 32768 + b * 2048) : (wC + l * 8192 + b * 512);
  __shared__ float red[256];
  __shared__ float e[2048];
  float m = -1e30f;
  for (int i = t; i < ntok; i += 256) m = fmaxf(m, s[i]);
  red[t] = m;
  __syncthreads();
  for (int h = 128; h; h >>= 1) { if (t < h) red[t] = fmaxf(red[t], red[t + h]); __syncthreads(); }
  const float smax = red[0];
  __syncthreads();
  float sum = 0.f;
  for (int i = t; i < ntok; i += 256) {
    const float ev = __expf(s[i] - smax) * (float)mk[i];
    e[i] = ev;
    sum += ev;
  }
  red[t] = sum;
  __syncthreads();
  for (int h = 128; h; h >>= 1) { if (t < h) red[t] += red[t + h]; __syncthreads(); }
  const float inv = 1.f / (red[0] + 1e-6f);
  for (int i = t; i < ntok; i += 256) w[i] = e[i] * inv;
}

// chunked pooling partials over all 4 layers. grid (16, 20): y<4 comp chunks, y>=4 prot
__global__ __launch_bounds__(256)
void poolpart(const float* __restrict__ wC, const float* __restrict__ wP,
              const float* __restrict__ cfeat, const float* __restrict__ pfeat,
              float* __restrict__ partC, float* __restrict__ partP) {
  const int b = blockIdx.x, y = blockIdx.y, d = threadIdx.x;
  const float* feat;
  const float* wb;
  int ls, tok0;
  float* part;
  if (y < 4) {
    feat = cfeat + (size_t)b * 512 * 256;
    wb = wC + b * 512; ls = 8192; tok0 = y * 128;
    part = partC + ((size_t)b * 4 + y) * 1024;
  } else {
    const int ch = y - 4;
    feat = pfeat + (size_t)b * 2048 * 256;
    wb = wP + b * 2048; ls = 32768; tok0 = ch * 128;
    part = partP + ((size_t)b * 16 + ch) * 1024;
  }
  float a0 = 0.f, a1 = 0.f, a2 = 0.f, a3 = 0.f;
  for (int tok = tok0; tok < tok0 + 128; tok++) {
    const float f = feat[(size_t)tok * 256 + d];
    a0 += wb[tok] * f;
    a1 += wb[ls + tok] * f;
    a2 += wb[2 * ls + tok] * f;
    a3 += wb[3 * ls + tok] * f;
  }
  part[d] = a0; part[256 + d] = a1; part[512 + d] = a2; part[768 + d] = a3;
}

// reduce partials -> pool[b][1024]. grid (16,2)
__global__ void poolreduce(const float* __restrict__ partC, const float* __restrict__ partP,
                           float* __restrict__ poolc, float* __restrict__ poolp) {
  const int b = blockIdx.x, t = threadIdx.x;
  if (blockIdx.y == 0) {
    for (int k = t; k < 1024; k += 256) {
      float s = 0.f;
      for (int ch = 0; ch < 4; ch++) s += partC[((size_t)b * 4 + ch) * 1024 + k];
      poolc[b * 1024 + k] = s;
    }
  } else {
    for (int k = t; k < 1024; k += 256) {
      float s = 0.f;
      for (int ch = 0; ch < 16; ch++) s += partP[((size_t)b * 16 + ch) * 1024 + k];
      poolp[b * 1024 + k] = s;
    }
  }
}

// out[b][n] = bias[n] + sum_k pool[b][k] * W[k][n]   (K=1024, N=256)
__global__ void final_kernel(const float* __restrict__ pool, const float* __restrict__ W,
                             const float* __restrict__ bias, float* __restrict__ outp) {
  const int b = blockIdx.x, n = threadIdx.x, q = threadIdx.y;
  __shared__ float red[4][256];
  float acc = 0.f;
  const float* p = pool + b * 1024 + q * 256;
  const float* w = W + (size_t)q * 256 * 256;
  for (int k = 0; k < 256; k++) acc += p[k] * w[(size_t)k * 256 + n];
  red[q][n] = acc;
  __syncthreads();
  if (q == 0) outp[b * 256 + n] = red[0][n] + red[1][n] + red[2][n] + red[3][n] + bias[n];
}

// ---------------------------------------------------------------------------
static inline void launch_gemm(hipStream_t s, const u16* X, long long xbs, int ldx,
                               const u16* Y, long long ybs, int ldy,
                               void* Out, long long obs, int ldo,
                               u16* Tout, long long tobs, int tldo,
                               int M, int N, int K, int nb, int flags,
                               const float* bias, const int* rm, int rms,
                               const int* cm, int cms) {
  dim3 g(N / 128, M / 128, nb);
  gemm_nt<<<g, dim3(256), 0, s>>>(X, xbs, ldx, Y, ybs, ldy, Out, obs, ldo,
                                  Tout, tobs, tldo, K, flags, bias, rm, rms, cm, cms);
}

extern "C" void kernel_launch(void* const* d_in, const int* in_sizes, int n_in,
                              void* d_out, int out_size, void* d_ws, size_t ws_size,
                              hipStream_t stream) {
  (void)in_sizes; (void)n_in; (void)out_size; (void)ws_size;
  enum { Bc = 16, LCc = 512, LPc = 2048, Dc = 256, Lc = 4 };

  const float* comp_feat = (const float*)d_in[0];
  const int*   comp_mask = (const int*)d_in[1];
  const float* prot_feat = (const float*)d_in[2];
  const int*   prot_mask = (const int*)d_in[3];
  const float* U     = (const float*)d_in[4];
  const float* W_p2c = (const float*)d_in[5];
  const float* b_p2c = (const float*)d_in[6];
  const float* W_c2p = (const float*)d_in[7];
  const float* b_c2p = (const float*)d_in[8];
  const float* W_hc  = (const float*)d_in[9];
  const float* b_hc  = (const float*)d_in[10];
  const float* W_hp  = (const float*)d_in[11];
  const float* b_hp  = (const float*)d_in[12];
  const float* W_ac  = (const float*)d_in[13];
  const float* b_ac  = (const float*)d_in[14];
  const float* W_ap  = (const float*)d_in[15];
  const float* b_ap  = (const float*)d_in[16];
  const float* W_cc  = (const float*)d_in[17];
  const float* b_cc  = (const float*)d_in[18];
  const float* W_cp  = (const float*)d_in[19];
  const float* b_cp  = (const float*)d_in[20];

  float* out_cf = (float*)d_out;                       // [16][256]
  float* out_pf = out_cf + Bc * Dc;                    // [16][256]
  float* CLW = out_pf + Bc * Dc;                       // [16][512][2048]
  float* PLW = CLW + (size_t)Bc * LCc * 2 * Dc * Lc;   // [16][2048][2048]

  char* wsp = (char*)d_ws;
  size_t off = 0;
  auto carve = [&](size_t bytes) -> char* {
    char* p = wsp + off;
    off += (bytes + 255) & ~(size_t)255;
    return p;
  };
  u16* cfb   = (u16*)carve((size_t)Bc * LCc * Dc * 2);          // 4.2 MB
  u16* pfb   = (u16*)carve((size_t)Bc * LPc * Dc * 2);          // 16.8 MB
  u16* Utb   = (u16*)carve((size_t)Lc * Dc * Dc * 2);
  u16* Wp2ct = (u16*)carve((size_t)Lc * Dc * Dc * 2);
  u16* Wc2pt = (u16*)carve((size_t)Lc * Dc * Dc * 2);
  u16* Whct  = (u16*)carve((size_t)Lc * Dc * Dc * 2);
  u16* Whpt  = (u16*)carve((size_t)Lc * Dc * Dc * 2);
  u16* CU_all  = (u16*)carve((size_t)Bc * LCc * Lc * Dc * 2);   // [8192][1024] 16.8 MB
  u16* C2Pt_all = (u16*)carve((size_t)Bc * Lc * Dc * LCc * 2);  // [b][1024][512] 16.8 MB
  u16* P2Ct_all = (u16*)carve((size_t)Bc * Lc * Dc * LPc * 2);  // [b][1024][2048] 67 MB
  u16* Ab  = (u16*)carve((size_t)Bc * LCc * LPc * 2);           // 33.5 MB
  u16* Atb = (u16*)carve((size_t)Bc * LCc * LPc * 2);           // 33.5 MB
  float* scoresC = (float*)carve((size_t)Lc * Bc * LCc * 4);
  float* scoresP = (float*)carve((size_t)Lc * Bc * LPc * 4);
  float* wCb = (float*)carve((size_t)Lc * Bc * LCc * 4);
  float* wPb = (float*)carve((size_t)Lc * Bc * LPc * 4);
  float* partC = (float*)carve((size_t)Bc * 4 * 1024 * 4);
  float* partP = (float*)carve((size_t)Bc * 16 * 1024 * 4);
  float* poolc = (float*)carve((size_t)Bc * 1024 * 4);
  float* poolp = (float*)carve((size_t)Bc * 1024 * 4);

  // --- init: bf16 features, transposed bf16 weights ---
  conv_bf16<<<dim3(Bc * LCc * Dc / 4 / 256), dim3(256), 0, stream>>>(comp_feat, cfb, Bc * LCc * Dc / 4);
  conv_bf16<<<dim3(Bc * LPc * Dc / 4 / 256), dim3(256), 0, stream>>>(prot_feat, pfb, Bc * LPc * Dc / 4);
  {
    dim3 wg(8, 8, Lc), wb(32, 8);
    wtrans<<<wg, wb, 0, stream>>>(U, Utb);
    wtrans<<<wg, wb, 0, stream>>>(W_p2c, Wp2ct);
    wtrans<<<wg, wb, 0, stream>>>(W_c2p, Wc2pt);
    wtrans<<<wg, wb, 0, stream>>>(W_hc, Whct);
    wtrans<<<wg, wb, 0, stream>>>(W_hp, Whpt);
  }

  const int LW = 2 * Dc * Lc;  // 2048

  // --- batched-over-layers weight GEMMs (N = 1024 = 4 x 256) ---
  // CU_all[tok][i*256+d] = cf @ U_i
  launch_gemm(stream, cfb, 0, Dc, Utb, 0, Dc, CU_all, 0, Lc * Dc, nullptr, 0, 0,
              Bc * LCc, Lc * Dc, Dc, 1, FLAG_NSTORE | FLAG_BF16, nullptr, nullptr, 0, nullptr, 0);
  // CLW tanh halves: col i*512 + d
  launch_gemm(stream, cfb, 0, Dc, Whct, 0, Dc, CLW, 0, LW, nullptr, 0, 0,
              Bc * LCc, Lc * Dc, Dc, 1, FLAG_NSTORE | FLAG_SPLITN | FLAG_BIAS | FLAG_TANH,
              b_hc, nullptr, 0, nullptr, 0);
  launch_gemm(stream, pfb, 0, Dc, Whpt, 0, Dc, PLW, 0, LW, nullptr, 0, 0,
              Bc * LPc, Lc * Dc, Dc, 1, FLAG_NSTORE | FLAG_SPLITN | FLAG_BIAS | FLAG_TANH,
              b_hp, nullptr, 0, nullptr, 0);
  // C2Pt_all[b][i*256+d][c] = tanh(cf @ W_c2p_i + b)^T   (per-b, transposed store)
  launch_gemm(stream, cfb, (long long)LCc * Dc, Dc, Wc2pt, 0, Dc, nullptr, 0, 0,
              C2Pt_all, (long long)Lc * Dc * LCc, LCc,
              LCc, Lc * Dc, Dc, Bc, FLAG_TSTORE | FLAG_BIAS | FLAG_TANH,
              b_c2p, nullptr, 0, nullptr, 0);
  // P2Ct_all[b][i*256+d][p]
  launch_gemm(stream, pfb, (long long)LPc * Dc, Dc, Wp2ct, 0, Dc, nullptr, 0, 0,
              P2Ct_all, (long long)Lc * Dc * LPc, LPc,
              LPc, Lc * Dc, Dc, Bc, FLAG_TSTORE | FLAG_BIAS | FLAG_TANH,
              b_p2c, nullptr, 0, nullptr, 0);

  for (int i = 0; i < Lc; i++) {
    // GEMM-1: A = tanh(CU_i · pf^T) * mask  -> A (normal bf16) + At (transposed)
    launch_gemm(stream, CU_all + i * Dc, (long long)LCc * Lc * Dc, Lc * Dc,
                pfb, (long long)LPc * Dc, Dc,
                Ab, (long long)LCc * LPc, LPc,
                Atb, (long long)LCc * LPc, LCc,
                LCc, LPc, Dc, Bc,
                FLAG_NSTORE | FLAG_TSTORE | FLAG_BF16 | FLAG_TANH | FLAG_MASK,
                nullptr, comp_mask, LCc, prot_mask, LPc);
    // GEMM-2: comp_cross = A · tanhP2C  [512 x 256, K=2048] -> CLW cols i*512+256..
    launch_gemm(stream, Ab, (long long)LCc * LPc, LPc,
                P2Ct_all + (size_t)i * Dc * LPc, (long long)Lc * Dc * LPc, LPc,
                CLW + i * 2 * Dc + Dc, (long long)LCc * LW, LW, nullptr, 0, 0,
                LCc, Dc, LPc, Bc, FLAG_NSTORE, nullptr, nullptr, 0, nullptr, 0);
    // GEMM-3: prot_cross = A^T · tanhC2P  [2048 x 256, K=512] -> PLW cols i*512+256..
    launch_gemm(stream, Atb, (long long)LCc * LPc, LCc,
                C2Pt_all + (size_t)i * Dc * LCc, (long long)Lc * Dc * LCc, LCc,
                PLW + i * 2 * Dc + Dc, (long long)LPc * LW, LW, nullptr, 0, 0,
                LPc, Dc, LCc, Bc, FLAG_NSTORE, nullptr, nullptr, 0, nullptr, 0);
    // attention scores (stashed; pooling happens once at the end)
    scores_kernel<<<dim3(Bc * LCc / 4), dim3(256), 0, stream>>>(
        CLW + i * 2 * Dc, LW, W_ac + i * 2 * Dc, b_ac + i, scoresC + i * Bc * LCc);
    scores_kernel<<<dim3(Bc * LPc / 4), dim3(256), 0, stream>>>(
        PLW + i * 2 * Dc, LW, W_ap + i * 2 * Dc, b_ap + i, scoresP + i * Bc * LPc);
  }

  // --- fused pooling over all layers ---
  softmax_w<<<dim3(Lc * Bc, 2), dim3(256), 0, stream>>>(scoresC, scoresP, comp_mask, prot_mask, wCb, wPb);
  poolpart<<<dim3(Bc, 20), dim3(256), 0, stream>>>(wCb, wPb, comp_feat, prot_feat, partC, partP);
  poolreduce<<<dim3(Bc, 2), dim3(256), 0, stream>>>(partC, partP, poolc, poolp);
  final_kernel<<<dim3(Bc), dim3(256, 4), 0, stream>>>(poolc, W_cc, b_cc, out_cf);
  final_kernel<<<dim3(Bc), dim3(256, 4), 0, stream>>>(poolp, W_cp, b_cp, out_pf);
}

// Round 3
// 856.216 us; speedup vs baseline: 1.7778x; 1.0305x over previous
//
#include <hip/hip_runtime.h>

typedef unsigned short u16;
typedef __attribute__((ext_vector_type(8))) short short8;
typedef __attribute__((ext_vector_type(4))) float f32x4;

#define FLAG_BIAS   1
#define FLAG_TANH   2
#define FLAG_MASK   4
#define FLAG_BF16   8
#define FLAG_NSTORE 16
#define FLAG_TSTORE 32
#define FLAG_SPLITN 64

__device__ __forceinline__ float fast_tanh(float x) {
  return 1.f - 2.f / (__expf(2.f * x) + 1.f);
}

__device__ __forceinline__ u16 f2bf(float f) {
  unsigned u = __float_as_uint(f);
  return (u16)((u + 0x7fffu + ((u >> 16) & 1u)) >> 16); // RNE
}

__device__ __forceinline__ void gload_lds16(const void* g, void* l) {
  __builtin_amdgcn_global_load_lds(
      (const __attribute__((address_space(1))) unsigned int*)g,
      (__attribute__((address_space(3))) unsigned int*)l, 16, 0, 0);
}

// ---------------------------------------------------------------------------
// Generic NT GEMM: Out[r][c] = sum_k X[r][k] * Y[c][k]   (both K-contiguous)
// 128x128 tile, BK=32, 4 waves of 64x64, mfma_f32_16x16x32_bf16.
// 2-phase double-buffered k-loop (stage t+1 before compute t, 1 barrier/iter).
// Optional split-K via blockIdx.z = b*kchunks + kc -> f32 partial slabs.
// ---------------------------------------------------------------------------
__global__ __launch_bounds__(256)
void gemm_nt(const u16* __restrict__ X, long long xbs, int ldx,
             const u16* __restrict__ Y, long long ybs, int ldy,
             void* __restrict__ Outv, long long obs, int ldo,
             u16* __restrict__ Tout, long long tobs, int tldo,
             int K, int kchunks, long long kcs, int flags,
             const float* __restrict__ bias,
             const int* __restrict__ rmask, int rms,
             const int* __restrict__ cmask, int cms) {
  __shared__ __align__(16) char smem[32768];
  const int t = threadIdx.x;
  const int lane = t & 63, wid = t >> 6;
  const int wr = (wid >> 1) * 64, wc = (wid & 1) * 64;
  int bz = blockIdx.z, kc = 0;
  if (kchunks > 1) { kc = bz & (kchunks - 1); bz >>= __builtin_ctz(kchunks); }
  const int Keff = K / kchunks, koff = kc * Keff;
  const int rb = blockIdx.y * 128;
  const int cb = blockIdx.x * 128;
  const u16* Xb = X + (size_t)bz * xbs + (size_t)rb * ldx + koff;
  const u16* Yb = Y + (size_t)bz * ybs + (size_t)cb * ldy + koff;
  const int srow = t >> 2, scol = (t & 3) * 8;

  f32x4 acc[4][4];
#pragma unroll
  for (int m = 0; m < 4; m++)
#pragma unroll
    for (int n = 0; n < 4; n++) acc[m][n] = (f32x4){0.f, 0.f, 0.f, 0.f};

  auto stage = [&](int buf, int kk) {
    char* dst = smem + buf * 16384 + t * 16;
#pragma unroll
    for (int j = 0; j < 2; j++) {
      gload_lds16(Xb + (size_t)(j * 64 + srow) * ldx + kk + scol, dst + j * 4096);
      gload_lds16(Yb + (size_t)(j * 64 + srow) * ldy + kk + scol, dst + 8192 + j * 4096);
    }
  };

  const int nt = Keff >> 5;
  stage(0, 0);
  __syncthreads();
  const int r16 = lane & 15, kh = (lane >> 4) * 8;
  for (int tt = 0; tt < nt; ++tt) {
    const int cur = tt & 1;
    if (tt + 1 < nt) stage(cur ^ 1, (tt + 1) * 32);
    const u16* lx = (const u16*)(smem + cur * 16384);
    const u16* ly = lx + 4096;
    short8 av[4], bv[4];
#pragma unroll
    for (int m = 0; m < 4; m++) av[m] = *(const short8*)&lx[(wr + m * 16 + r16) * 32 + kh];
#pragma unroll
    for (int n = 0; n < 4; n++) bv[n] = *(const short8*)&ly[(wc + n * 16 + r16) * 32 + kh];
#pragma unroll
    for (int m = 0; m < 4; m++)
#pragma unroll
      for (int n = 0; n < 4; n++)
        acc[m][n] = __builtin_amdgcn_mfma_f32_16x16x32_bf16(av[m], bv[n], acc[m][n], 0, 0, 0);
    __syncthreads();
  }

  // --- register-stage epilogue math (bias / tanh / mask) ---
  if (flags & (FLAG_BIAS | FLAG_TANH | FLAG_MASK)) {
#pragma unroll
    for (int n = 0; n < 4; n++) {
      const int c = cb + wc + n * 16 + (lane & 15);
      const float bcol = (flags & FLAG_BIAS) ? bias[c] : 0.f;
      const float cmv = (flags & FLAG_MASK) ? (float)cmask[(size_t)bz * cms + c] : 1.f;
#pragma unroll
      for (int m = 0; m < 4; m++) {
#pragma unroll
        for (int j = 0; j < 4; j++) {
          float v = acc[m][n][j] + bcol;
          if (flags & FLAG_TANH) v = fast_tanh(v);
          if (flags & FLAG_MASK) {
            const int r = rb + wr + m * 16 + ((lane >> 4) << 2) + j;
            v *= cmv * (float)rmask[(size_t)bz * rms + r];
          }
          acc[m][n][j] = v;
        }
      }
    }
  }

  const int strip_r = wid >> 1, strip_c = wid & 1;
  const int ocb = (flags & FLAG_SPLITN) ? ((cb >> 8) * 512 + (cb & 255)) : cb;

  if (flags & FLAG_NSTORE) {
#pragma unroll
    for (int m = 0; m < 4; m++) {
      __syncthreads();
      if (flags & FLAG_BF16) {
        u16* bb = (u16*)smem;  // [32][136]
#pragma unroll
        for (int n = 0; n < 4; n++)
#pragma unroll
          for (int j = 0; j < 4; j++)
            bb[(strip_r * 16 + ((lane >> 4) << 2) + j) * 136 + strip_c * 64 + n * 16 + (lane & 15)] =
                f2bf(acc[m][n][j]);
        __syncthreads();
        const int lr = t >> 3, c0 = (t & 7) * 16;
        const int g = rb + (lr >> 4) * 64 + m * 16 + (lr & 15);
        u16* op = (u16*)Outv + (size_t)bz * obs + (size_t)g * ldo + ocb + c0;
#pragma unroll
        for (int q = 0; q < 2; q++)
          ((uint4*)op)[q] = ((const uint4*)&bb[lr * 136 + c0])[q];
      } else {
        float* bb = (float*)smem;  // [32][132]
#pragma unroll
        for (int n = 0; n < 4; n++)
#pragma unroll
          for (int j = 0; j < 4; j++)
            bb[(strip_r * 16 + ((lane >> 4) << 2) + j) * 132 + strip_c * 64 + n * 16 + (lane & 15)] =
                acc[m][n][j];
        __syncthreads();
        const int lr = t >> 3, c0 = (t & 7) * 16;
        const int g = rb + (lr >> 4) * 64 + m * 16 + (lr & 15);
        float* op = (float*)Outv + (size_t)kc * kcs + (size_t)bz * obs + (size_t)g * ldo + ocb + c0;
#pragma unroll
        for (int q = 0; q < 4; q++)
          ((float4*)op)[q] = ((const float4*)&bb[lr * 132 + c0])[q];
      }
    }
  }

  if (flags & FLAG_TSTORE) {
#pragma unroll
    for (int n = 0; n < 4; n++) {
      __syncthreads();
      u16* bb = (u16*)smem;  // [32][136]
#pragma unroll
      for (int m = 0; m < 4; m++)
#pragma unroll
        for (int j = 0; j < 4; j++)
          bb[(strip_c * 16 + (lane & 15)) * 136 + strip_r * 64 + m * 16 + ((lane >> 4) << 2) + j] =
              f2bf(acc[m][n][j]);
      __syncthreads();
      const int lp = t >> 3, r0 = (t & 7) * 16;
      const int cg = cb + (lp >> 4) * 64 + n * 16 + (lp & 15);
      u16* op = Tout + (size_t)bz * tobs + (size_t)cg * tldo + rb + r0;
#pragma unroll
      for (int q = 0; q < 2; q++)
        ((uint4*)op)[q] = ((const uint4*)&bb[lp * 136 + r0])[q];
    }
  }
}

// reduce split-K partials: CLW[b][r][coloff + c] = sum_kc part[kc][b][r][c]
__global__ void ksum(const float* __restrict__ part, float* __restrict__ out,
                     long long obs, int ldo, int coloff, int kchunks, long long kcs) {
  const int r = blockIdx.x, b = blockIdx.y, c = threadIdx.x;
  const size_t base = ((size_t)b * gridDim.x + r) * 256 + c;
  float s = 0.f;
  for (int kc = 0; kc < kchunks; kc++) s += part[(size_t)kc * kcs + base];
  out[(size_t)b * obs + (size_t)r * ldo + coloff + c] = s;
}

// f32 [256][256] -> bf16 transposed, per matrix (z)
__global__ void wtrans(const float* __restrict__ in, u16* __restrict__ out) {
  __shared__ float tl[32][33];
  const size_t bo = (size_t)blockIdx.z * 256 * 256;
  const int c0 = blockIdx.x * 32, r0 = blockIdx.y * 32;
  for (int i = threadIdx.y; i < 32; i += 8)
    tl[i][threadIdx.x] = in[bo + (size_t)(r0 + i) * 256 + c0 + threadIdx.x];
  __syncthreads();
  for (int i = threadIdx.y; i < 32; i += 8)
    out[bo + (size_t)(c0 + i) * 256 + r0 + threadIdx.x] = f2bf(tl[threadIdx.x][i]);
}

__global__ void conv_bf16(const float* __restrict__ in, u16* __restrict__ out, int n4) {
  const int i = blockIdx.x * 256 + threadIdx.x;
  if (i >= n4) return;
  const float4 v = ((const float4*)in)[i];
  ushort4 o;
  o.x = f2bf(v.x); o.y = f2bf(v.y); o.z = f2bf(v.z); o.w = f2bf(v.w);
  ((ushort4*)out)[i] = o;
}

// one wave per token: score = dot(comb[tok, 0:512], wvec) + bias
__global__ void scores_kernel(const float* __restrict__ comb, int tokstride,
                              const float* __restrict__ wvec, const float* __restrict__ bsc,
                              float* __restrict__ outp) {
  const int lane = threadIdx.x & 63, wid = threadIdx.x >> 6;
  const int tok = blockIdx.x * 4 + wid;
  const float* p = comb + (size_t)tok * tokstride + lane * 8;
  const float4 a = *(const float4*)p, b = *(const float4*)(p + 4);
  const float* wp = wvec + lane * 8;
  const float4 wa = *(const float4*)wp, wb = *(const float4*)(wp + 4);
  float s = a.x * wa.x + a.y * wa.y + a.z * wa.z + a.w * wa.w +
            b.x * wb.x + b.y * wb.y + b.z * wb.z + b.w * wb.w;
#pragma unroll
  for (int off = 32; off; off >>= 1) s += __shfl_down(s, off);
  if (lane == 0) outp[tok] = s + bsc[0];
}

// masked softmax -> normalized weights. grid(64, 2): x = l*16+b, y: 0=comp 1=prot
__global__ __launch_bounds__(256)
void softmax_w(const float* __restrict__ sC, const float* __restrict__ sP,
               const int* __restrict__ cmask, const int* __restrict__ pmask,
               float* __restrict__ wC, float* __restrict__ wP) {
  const int l = blockIdx.x >> 4, b = blockIdx.x & 15, t = threadIdx.x;
  const int ntok = blockIdx.y ? 2048 : 512;
  const float* s = blockIdx.y ? (sP + l * 32768 + b * 2048) : (sC + l * 8192 + b * 512);
  const int* mk = blockIdx.y ? (pmask + b * 2048) : (cmask + b * 512);
  float* w = blockIdx.y ? (wP + l * 32768 + b * 2048) : (wC + l * 8192 + b * 512);
  __shared__ float red[256];
  __shared__ float e[2048];
  float m = -1e30f;
  for (int i = t; i < ntok; i += 256) m = fmaxf(m, s[i]);
  red[t] = m;
  __syncthreads();
  for (int h = 128; h; h >>= 1) { if (t < h) red[t] = fmaxf(red[t], red[t + h]); __syncthreads(); }
  const float smax = red[0];
  __syncthreads();
  float sum = 0.f;
  for (int i = t; i < ntok; i += 256) {
    const float ev = __expf(s[i] - smax) * (float)mk[i];
    e[i] = ev;
    sum += ev;
  }
  red[t] = sum;
  __syncthreads();
  for (int h = 128; h; h >>= 1) { if (t < h) red[t] += red[t + h]; __syncthreads(); }
  const float inv = 1.f / (red[0] + 1e-6f);
  for (int i = t; i < ntok; i += 256) w[i] = e[i] * inv;
}

// chunked pooling partials over all 4 layers. grid (16, 20): y<4 comp chunks, y>=4 prot
__global__ __launch_bounds__(256)
void poolpart(const float* __restrict__ wC, const float* __restrict__ wP,
              const float* __restrict__ cfeat, const float* __restrict__ pfeat,
              float* __restrict__ partC, float* __restrict__ partP) {
  const int b = blockIdx.x, y = blockIdx.y, d = threadIdx.x;
  const float* feat;
  const float* wb;
  int ls, tok0;
  float* part;
  if (y < 4) {
    feat = cfeat + (size_t)b * 512 * 256;
    wb = wC + b * 512; ls = 8192; tok0 = y * 128;
    part = partC + ((size_t)b * 4 + y) * 1024;
  } else {
    const int ch = y - 4;
    feat = pfeat + (size_t)b * 2048 * 256;
    wb = wP + b * 2048; ls = 32768; tok0 = ch * 128;
    part = partP + ((size_t)b * 16 + ch) * 1024;
  }
  float a0 = 0.f, a1 = 0.f, a2 = 0.f, a3 = 0.f;
  for (int tok = tok0; tok < tok0 + 128; tok++) {
    const float f = feat[(size_t)tok * 256 + d];
    a0 += wb[tok] * f;
    a1 += wb[ls + tok] * f;
    a2 += wb[2 * ls + tok] * f;
    a3 += wb[3 * ls + tok] * f;
  }
  part[d] = a0; part[256 + d] = a1; part[512 + d] = a2; part[768 + d] = a3;
}

// reduce partials -> pool[b][1024]. grid (16,2)
__global__ void poolreduce(const float* __restrict__ partC, const float* __restrict__ partP,
                           float* __restrict__ poolc, float* __restrict__ poolp) {
  const int b = blockIdx.x, t = threadIdx.x;
  if (blockIdx.y == 0) {
    for (int k = t; k < 1024; k += 256) {
      float s = 0.f;
      for (int ch = 0; ch < 4; ch++) s += partC[((size_t)b * 4 + ch) * 1024 + k];
      poolc[b * 1024 + k] = s;
    }
  } else {
    for (int k = t; k < 1024; k += 256) {
      float s = 0.f;
      for (int ch = 0; ch < 16; ch++) s += partP[((size_t)b * 16 + ch) * 1024 + k];
      poolp[b * 1024 + k] = s;
    }
  }
}

// out[b][n] = bias[n] + sum_k pool[b][k] * W[k][n]   (K=1024, N=256)
__global__ void final_kernel(const float* __restrict__ pool, const float* __restrict__ W,
                             const float* __restrict__ bias, float* __restrict__ outp) {
  const int b = blockIdx.x, n = threadIdx.x, q = threadIdx.y;
  __shared__ float red[4][256];
  float acc = 0.f;
  const float* p = pool + b * 1024 + q * 256;
  const float* w = W + (size_t)q * 256 * 256;
  for (int k = 0; k < 256; k++) acc += p[k] * w[(size_t)k * 256 + n];
  red[q][n] = acc;
  __syncthreads();
  if (q == 0) outp[b * 256 + n] = red[0][n] + red[1][n] + red[2][n] + red[3][n] + bias[n];
}

// ---------------------------------------------------------------------------
static inline void launch_gemm(hipStream_t s, const u16* X, long long xbs, int ldx,
                               const u16* Y, long long ybs, int ldy,
                               void* Out, long long obs, int ldo,
                               u16* Tout, long long tobs, int tldo,
                               int M, int N, int K, int nb, int kchunks, long long kcs,
                               int flags, const float* bias, const int* rm, int rms,
                               const int* cm, int cms) {
  dim3 g(N / 128, M / 128, nb * kchunks);
  gemm_nt<<<g, dim3(256), 0, s>>>(X, xbs, ldx, Y, ybs, ldy, Out, obs, ldo,
                                  Tout, tobs, tldo, K, kchunks, kcs, flags,
                                  bias, rm, rms, cm, cms);
}

extern "C" void kernel_launch(void* const* d_in, const int* in_sizes, int n_in,
                              void* d_out, int out_size, void* d_ws, size_t ws_size,
                              hipStream_t stream) {
  (void)in_sizes; (void)n_in; (void)out_size; (void)ws_size;
  enum { Bc = 16, LCc = 512, LPc = 2048, Dc = 256, Lc = 4 };

  const float* comp_feat = (const float*)d_in[0];
  const int*   comp_mask = (const int*)d_in[1];
  const float* prot_feat = (const float*)d_in[2];
  const int*   prot_mask = (const int*)d_in[3];
  const float* U     = (const float*)d_in[4];
  const float* W_p2c = (const float*)d_in[5];
  const float* b_p2c = (const float*)d_in[6];
  const float* W_c2p = (const float*)d_in[7];
  const float* b_c2p = (const float*)d_in[8];
  const float* W_hc  = (const float*)d_in[9];
  const float* b_hc  = (const float*)d_in[10];
  const float* W_hp  = (const float*)d_in[11];
  const float* b_hp  = (const float*)d_in[12];
  const float* W_ac  = (const float*)d_in[13];
  const float* b_ac  = (const float*)d_in[14];
  const float* W_ap  = (const float*)d_in[15];
  const float* b_ap  = (const float*)d_in[16];
  const float* W_cc  = (const float*)d_in[17];
  const float* b_cc  = (const float*)d_in[18];
  const float* W_cp  = (const float*)d_in[19];
  const float* b_cp  = (const float*)d_in[20];

  float* out_cf = (float*)d_out;                       // [16][256]
  float* out_pf = out_cf + Bc * Dc;                    // [16][256]
  float* CLW = out_pf + Bc * Dc;                       // [16][512][2048]
  float* PLW = CLW + (size_t)Bc * LCc * 2 * Dc * Lc;   // [16][2048][2048]

  char* wsp = (char*)d_ws;
  size_t off = 0;
  auto carve = [&](size_t bytes) -> char* {
    char* p = wsp + off;
    off += (bytes + 255) & ~(size_t)255;
    return p;
  };
  u16* cfb   = (u16*)carve((size_t)Bc * LCc * Dc * 2);          // 4.2 MB
  u16* pfb   = (u16*)carve((size_t)Bc * LPc * Dc * 2);          // 16.8 MB
  u16* Utb   = (u16*)carve((size_t)Lc * Dc * Dc * 2);
  u16* Wp2ct = (u16*)carve((size_t)Lc * Dc * Dc * 2);
  u16* Wc2pt = (u16*)carve((size_t)Lc * Dc * Dc * 2);
  u16* Whct  = (u16*)carve((size_t)Lc * Dc * Dc * 2);
  u16* Whpt  = (u16*)carve((size_t)Lc * Dc * Dc * 2);
  u16* CU_all  = (u16*)carve((size_t)Bc * LCc * Lc * Dc * 2);   // 16.8 MB
  u16* C2Pt_all = (u16*)carve((size_t)Bc * Lc * Dc * LCc * 2);  // 16.8 MB
  u16* P2Ct_all = (u16*)carve((size_t)Bc * Lc * Dc * LPc * 2);  // 67 MB
  u16* Ab  = (u16*)carve((size_t)Bc * LCc * LPc * 2);           // 33.5 MB
  u16* Atb = (u16*)carve((size_t)Bc * LCc * LPc * 2);           // 33.5 MB
  float* kpart = (float*)carve((size_t)4 * Bc * LCc * Dc * 4);  // 33.5 MB split-K partials
  float* scoresC = (float*)carve((size_t)Lc * Bc * LCc * 4);
  float* scoresP = (float*)carve((size_t)Lc * Bc * LPc * 4);
  float* wCb = (float*)carve((size_t)Lc * Bc * LCc * 4);
  float* wPb = (float*)carve((size_t)Lc * Bc * LPc * 4);
  float* partC = (float*)carve((size_t)Bc * 4 * 1024 * 4);
  float* partP = (float*)carve((size_t)Bc * 16 * 1024 * 4);
  float* poolc = (float*)carve((size_t)Bc * 1024 * 4);
  float* poolp = (float*)carve((size_t)Bc * 1024 * 4);

  // --- init: bf16 features, transposed bf16 weights ---
  conv_bf16<<<dim3(Bc * LCc * Dc / 4 / 256), dim3(256), 0, stream>>>(comp_feat, cfb, Bc * LCc * Dc / 4);
  conv_bf16<<<dim3(Bc * LPc * Dc / 4 / 256), dim3(256), 0, stream>>>(prot_feat, pfb, Bc * LPc * Dc / 4);
  {
    dim3 wg(8, 8, Lc), wb(32, 8);
    wtrans<<<wg, wb, 0, stream>>>(U, Utb);
    wtrans<<<wg, wb, 0, stream>>>(W_p2c, Wp2ct);
    wtrans<<<wg, wb, 0, stream>>>(W_c2p, Wc2pt);
    wtrans<<<wg, wb, 0, stream>>>(W_hc, Whct);
    wtrans<<<wg, wb, 0, stream>>>(W_hp, Whpt);
  }

  const int LW = 2 * Dc * Lc;  // 2048

  // --- batched-over-layers weight GEMMs (N = 1024 = 4 x 256) ---
  launch_gemm(stream, cfb, 0, Dc, Utb, 0, Dc, CU_all, 0, Lc * Dc, nullptr, 0, 0,
              Bc * LCc, Lc * Dc, Dc, 1, 1, 0, FLAG_NSTORE | FLAG_BF16,
              nullptr, nullptr, 0, nullptr, 0);
  launch_gemm(stream, cfb, 0, Dc, Whct, 0, Dc, CLW, 0, LW, nullptr, 0, 0,
              Bc * LCc, Lc * Dc, Dc, 1, 1, 0,
              FLAG_NSTORE | FLAG_SPLITN | FLAG_BIAS | FLAG_TANH,
              b_hc, nullptr, 0, nullptr, 0);
  launch_gemm(stream, pfb, 0, Dc, Whpt, 0, Dc, PLW, 0, LW, nullptr, 0, 0,
              Bc * LPc, Lc * Dc, Dc, 1, 1, 0,
              FLAG_NSTORE | FLAG_SPLITN | FLAG_BIAS | FLAG_TANH,
              b_hp, nullptr, 0, nullptr, 0);
  launch_gemm(stream, cfb, (long long)LCc * Dc, Dc, Wc2pt, 0, Dc, nullptr, 0, 0,
              C2Pt_all, (long long)Lc * Dc * LCc, LCc,
              LCc, Lc * Dc, Dc, Bc, 1, 0, FLAG_TSTORE | FLAG_BIAS | FLAG_TANH,
              b_c2p, nullptr, 0, nullptr, 0);
  launch_gemm(stream, pfb, (long long)LPc * Dc, Dc, Wp2ct, 0, Dc, nullptr, 0, 0,
              P2Ct_all, (long long)Lc * Dc * LPc, LPc,
              LPc, Lc * Dc, Dc, Bc, 1, 0, FLAG_TSTORE | FLAG_BIAS | FLAG_TANH,
              b_p2c, nullptr, 0, nullptr, 0);

  for (int i = 0; i < Lc; i++) {
    // GEMM-1: A = tanh(CU_i · pf^T) * mask  -> A (normal bf16) + At (transposed)
    launch_gemm(stream, CU_all + i * Dc, (long long)LCc * Lc * Dc, Lc * Dc,
                pfb, (long long)LPc * Dc, Dc,
                Ab, (long long)LCc * LPc, LPc,
                Atb, (long long)LCc * LPc, LCc,
                LCc, LPc, Dc, Bc, 1, 0,
                FLAG_NSTORE | FLAG_TSTORE | FLAG_BF16 | FLAG_TANH | FLAG_MASK,
                nullptr, comp_mask, LCc, prot_mask, LPc);
    // GEMM-2: comp_cross = A · tanhP2C  [512 x 256, K=2048] split-K=4 -> partials
    launch_gemm(stream, Ab, (long long)LCc * LPc, LPc,
                P2Ct_all + (size_t)i * Dc * LPc, (long long)Lc * Dc * LPc, LPc,
                kpart, (long long)LCc * Dc, Dc, nullptr, 0, 0,
                LCc, Dc, LPc, Bc, 4, (long long)Bc * LCc * Dc,
                FLAG_NSTORE, nullptr, nullptr, 0, nullptr, 0);
    ksum<<<dim3(LCc, Bc), dim3(256), 0, stream>>>(kpart, CLW, (long long)LCc * LW, LW,
                                                  i * 2 * Dc + Dc, 4, (long long)Bc * LCc * Dc);
    // GEMM-3: prot_cross = A^T · tanhC2P  [2048 x 256, K=512] -> PLW cols i*512+256..
    launch_gemm(stream, Atb, (long long)LCc * LPc, LCc,
                C2Pt_all + (size_t)i * Dc * LCc, (long long)Lc * Dc * LCc, LCc,
                PLW + i * 2 * Dc + Dc, (long long)LPc * LW, LW, nullptr, 0, 0,
                LPc, Dc, LCc, Bc, 1, 0, FLAG_NSTORE, nullptr, nullptr, 0, nullptr, 0);
    // attention scores (stashed; pooling happens once at the end)
    scores_kernel<<<dim3(Bc * LCc / 4), dim3(256), 0, stream>>>(
        CLW + i * 2 * Dc, LW, W_ac + i * 2 * Dc, b_ac + i, scoresC + i * Bc * LCc);
    scores_kernel<<<dim3(Bc * LPc / 4), dim3(256), 0, stream>>>(
        PLW + i * 2 * Dc, LW, W_ap + i * 2 * Dc, b_ap + i, scoresP + i * Bc * LPc);
  }

  // --- fused pooling over all layers ---
  softmax_w<<<dim3(Lc * Bc, 2), dim3(256), 0, stream>>>(scoresC, scoresP, comp_mask, prot_mask, wCb, wPb);
  poolpart<<<dim3(Bc, 20), dim3(256), 0, stream>>>(wCb, wPb, comp_feat, prot_feat, partC, partP);
  poolreduce<<<dim3(Bc, 2), dim3(256), 0, stream>>>(partC, partP, poolc, poolp);
  final_kernel<<<dim3(Bc), dim3(256, 4), 0, stream>>>(poolc, W_cc, b_cc, out_cf);
  final_kernel<<<dim3(Bc), dim3(256, 4), 0, stream>>>(poolp, W_cp, b_cp, out_pf);
}

// Round 4
// 847.211 us; speedup vs baseline: 1.7967x; 1.0106x over previous
//
#include <hip/hip_runtime.h>

typedef unsigned short u16;
typedef __attribute__((ext_vector_type(8))) short short8;
typedef __attribute__((ext_vector_type(4))) float f32x4;

#define FLAG_BIAS   1
#define FLAG_TANH   2
#define FLAG_MASK   4
#define FLAG_BF16   8
#define FLAG_NSTORE 16
#define FLAG_TSTORE 32
#define FLAG_SPLITN 64

__device__ __forceinline__ float fast_tanh(float x) {
  return 1.f - 2.f / (__expf(2.f * x) + 1.f);
}

__device__ __forceinline__ u16 f2bf(float f) {
  unsigned u = __float_as_uint(f);
  return (u16)((u + 0x7fffu + ((u >> 16) & 1u)) >> 16); // RNE
}

__device__ __forceinline__ void gload_lds16(const void* g, void* l) {
  __builtin_amdgcn_global_load_lds(
      (const __attribute__((address_space(1))) unsigned int*)g,
      (__attribute__((address_space(3))) unsigned int*)l, 16, 0, 0);
}

// ---------------------------------------------------------------------------
// Generic NT GEMM: Out[r][c] = sum_k X[r][k] * Y[c][k]   (both K-contiguous)
// 128x128 tile, BK=32, 4 waves of 64x64, mfma_f32_16x16x32_bf16, 2-phase dbuf.
// blockIdx.z = l*16 + b (batch bz = z&15, layer lz = z>>4); all address terms
// additive: ptr + bz*bs + lz*ls + row*ld (+ ocol for output column base).
// ---------------------------------------------------------------------------
__global__ __launch_bounds__(256)
void gemm_nt(const u16* __restrict__ X, long long xbs, long long xls, int ldx,
             const u16* __restrict__ Y, long long ybs, long long yls, int ldy,
             void* __restrict__ Outv, long long obs, long long ols, int obase, int ldo,
             u16* __restrict__ Tout, long long tobs, long long tols, int tldo,
             int K, int flags,
             const float* __restrict__ bias,
             const int* __restrict__ rmask, int rms,
             const int* __restrict__ cmask, int cms) {
  __shared__ __align__(16) char smem[34816];
  const int t = threadIdx.x;
  const int lane = t & 63, wid = t >> 6;
  const int wr = (wid >> 1) * 64, wc = (wid & 1) * 64;
  const int bz = blockIdx.z & 15, lz = blockIdx.z >> 4;
  const int rb = blockIdx.y * 128;
  const int cb = blockIdx.x * 128;
  const u16* Xb = X + (size_t)bz * xbs + (size_t)lz * xls + (size_t)rb * ldx;
  const u16* Yb = Y + (size_t)bz * ybs + (size_t)lz * yls + (size_t)cb * ldy;
  const int srow = t >> 2, scol = (t & 3) * 8;

  f32x4 acc[4][4];
#pragma unroll
  for (int m = 0; m < 4; m++)
#pragma unroll
    for (int n = 0; n < 4; n++) acc[m][n] = (f32x4){0.f, 0.f, 0.f, 0.f};

  auto stage = [&](int buf, int kk) {
    char* dst = smem + buf * 16384 + t * 16;
#pragma unroll
    for (int j = 0; j < 2; j++) {
      gload_lds16(Xb + (size_t)(j * 64 + srow) * ldx + kk + scol, dst + j * 4096);
      gload_lds16(Yb + (size_t)(j * 64 + srow) * ldy + kk + scol, dst + 8192 + j * 4096);
    }
  };

  const int nt = K >> 5;
  stage(0, 0);
  __syncthreads();
  const int r16 = lane & 15, kh = (lane >> 4) * 8;
  for (int tt = 0; tt < nt; ++tt) {
    const int cur = tt & 1;
    if (tt + 1 < nt) stage(cur ^ 1, (tt + 1) * 32);
    const u16* lx = (const u16*)(smem + cur * 16384);
    const u16* ly = lx + 4096;
    short8 av[4], bv[4];
#pragma unroll
    for (int m = 0; m < 4; m++) av[m] = *(const short8*)&lx[(wr + m * 16 + r16) * 32 + kh];
#pragma unroll
    for (int n = 0; n < 4; n++) bv[n] = *(const short8*)&ly[(wc + n * 16 + r16) * 32 + kh];
#pragma unroll
    for (int m = 0; m < 4; m++)
#pragma unroll
      for (int n = 0; n < 4; n++)
        acc[m][n] = __builtin_amdgcn_mfma_f32_16x16x32_bf16(av[m], bv[n], acc[m][n], 0, 0, 0);
    __syncthreads();
  }

  // --- register-stage epilogue math (bias / tanh / mask) ---
  if (flags & (FLAG_BIAS | FLAG_TANH | FLAG_MASK)) {
#pragma unroll
    for (int n = 0; n < 4; n++) {
      const int c = cb + wc + n * 16 + (lane & 15);
      const float bcol = (flags & FLAG_BIAS) ? bias[c] : 0.f;
      const float cmv = (flags & FLAG_MASK) ? (float)cmask[(size_t)bz * cms + c] : 1.f;
#pragma unroll
      for (int m = 0; m < 4; m++) {
#pragma unroll
        for (int j = 0; j < 4; j++) {
          float v = acc[m][n][j] + bcol;
          if (flags & FLAG_TANH) v = fast_tanh(v);
          if (flags & FLAG_MASK) {
            const int r = rb + wr + m * 16 + ((lane >> 4) << 2) + j;
            v *= cmv * (float)rmask[(size_t)bz * rms + r];
          }
          acc[m][n][j] = v;
        }
      }
    }
  }

  const size_t ocol = (flags & FLAG_SPLITN) ? (size_t)((cb >> 8) * 512 + (cb & 255))
                                            : (size_t)obase + (size_t)lz * ols + cb;

  if (flags & FLAG_NSTORE) {
    if (flags & FLAG_BF16) {  // 1 pass: full 128x128 bf16 bounce
      __syncthreads();
      u16* bb = (u16*)smem;  // [128][136]
#pragma unroll
      for (int m = 0; m < 4; m++)
#pragma unroll
        for (int n = 0; n < 4; n++)
#pragma unroll
          for (int j = 0; j < 4; j++)
            bb[(wr + m * 16 + ((lane >> 4) << 2) + j) * 136 + wc + n * 16 + (lane & 15)] =
                f2bf(acc[m][n][j]);
      __syncthreads();
      const int row = t >> 1, h = (t & 1) * 64;
      u16* op = (u16*)Outv + (size_t)bz * obs + (size_t)(rb + row) * ldo + ocol + h;
      const u16* src = &bb[row * 136 + h];
#pragma unroll
      for (int q = 0; q < 8; q++) ((uint4*)op)[q] = ((const uint4*)src)[q];
    } else {  // 2 passes: 64x128 f32 bounce
#pragma unroll
      for (int mp = 0; mp < 2; mp++) {
        __syncthreads();
        float* bb = (float*)smem;  // [64][132]
#pragma unroll
        for (int q = 0; q < 2; q++) {
          const int m = 2 * mp + q;
#pragma unroll
          for (int n = 0; n < 4; n++)
#pragma unroll
            for (int j = 0; j < 4; j++)
              bb[((wid >> 1) * 32 + q * 16 + ((lane >> 4) << 2) + j) * 132 +
                 wc + n * 16 + (lane & 15)] = acc[m][n][j];
        }
        __syncthreads();
        const int lr = t >> 2, c0 = (t & 3) * 32;
        const int g = rb + (lr >> 5) * 64 + mp * 32 + (lr & 31);
        float* op = (float*)Outv + (size_t)bz * obs + (size_t)g * ldo + ocol + c0;
        const float* src = &bb[lr * 132 + c0];
#pragma unroll
        for (int q2 = 0; q2 < 8; q2++) ((float4*)op)[q2] = ((const float4*)src)[q2];
      }
    }
  }

  if (flags & FLAG_TSTORE) {  // 1 pass: transposed 128x128 bf16
    __syncthreads();
    u16* bb = (u16*)smem;  // [128][136], row index = output col
#pragma unroll
    for (int m = 0; m < 4; m++)
#pragma unroll
      for (int n = 0; n < 4; n++)
#pragma unroll
        for (int j = 0; j < 4; j++)
          bb[(wc + n * 16 + (lane & 15)) * 136 + wr + m * 16 + ((lane >> 4) << 2) + j] =
              f2bf(acc[m][n][j]);
    __syncthreads();
    const int col = t >> 1, h = (t & 1) * 64;
    u16* op = Tout + (size_t)lz * tols + (size_t)bz * tobs + (size_t)(cb + col) * tldo + rb + h;
    const u16* src = &bb[col * 136 + h];
#pragma unroll
    for (int q = 0; q < 8; q++) ((uint4*)op)[q] = ((const uint4*)src)[q];
  }
}

// f32 [256][256] -> bf16 transposed, per matrix (z)
__global__ void wtrans(const float* __restrict__ in, u16* __restrict__ out) {
  __shared__ float tl[32][33];
  const size_t bo = (size_t)blockIdx.z * 256 * 256;
  const int c0 = blockIdx.x * 32, r0 = blockIdx.y * 32;
  for (int i = threadIdx.y; i < 32; i += 8)
    tl[i][threadIdx.x] = in[bo + (size_t)(r0 + i) * 256 + c0 + threadIdx.x];
  __syncthreads();
  for (int i = threadIdx.y; i < 32; i += 8)
    out[bo + (size_t)(c0 + i) * 256 + r0 + threadIdx.x] = f2bf(tl[threadIdx.x][i]);
}

__global__ void conv_bf16(const float* __restrict__ in, u16* __restrict__ out, int n4) {
  const int i = blockIdx.x * 256 + threadIdx.x;
  if (i >= n4) return;
  const float4 v = ((const float4*)in)[i];
  ushort4 o;
  o.x = f2bf(v.x); o.y = f2bf(v.y); o.z = f2bf(v.z); o.w = f2bf(v.w);
  ((ushort4*)out)[i] = o;
}

// wave per token, layer = blockIdx.y: score = dot(comb[tok, l*512 : l*512+512], wvec_l)
__global__ void scores_kernel(const float* __restrict__ comb, int tokstride,
                              const float* __restrict__ wvec, const float* __restrict__ bsc,
                              float* __restrict__ outp, int ntoks) {
  const int l = blockIdx.y;
  const int lane = threadIdx.x & 63, wid = threadIdx.x >> 6;
  const int tok = blockIdx.x * 4 + wid;
  const float* p = comb + (size_t)tok * tokstride + (size_t)l * 512 + lane * 8;
  const float4 a = *(const float4*)p, b = *(const float4*)(p + 4);
  const float* wp = wvec + (size_t)l * 512 + lane * 8;
  const float4 wa = *(const float4*)wp, wb = *(const float4*)(wp + 4);
  float s = a.x * wa.x + a.y * wa.y + a.z * wa.z + a.w * wa.w +
            b.x * wb.x + b.y * wb.y + b.z * wb.z + b.w * wb.w;
#pragma unroll
  for (int off = 32; off; off >>= 1) s += __shfl_down(s, off);
  if (lane == 0) outp[(size_t)l * ntoks + tok] = s + bsc[l];
}

// masked softmax -> normalized weights. grid(64, 2): x = l*16+b, y: 0=comp 1=prot
__global__ __launch_bounds__(256)
void softmax_w(const float* __restrict__ sC, const float* __restrict__ sP,
               const int* __restrict__ cmask, const int* __restrict__ pmask,
               float* __restrict__ wC, float* __restrict__ wP) {
  const int l = blockIdx.x >> 4, b = blockIdx.x & 15, t = threadIdx.x;
  const int ntok = blockIdx.y ? 2048 : 512;
  const float* s = blockIdx.y ? (sP + l * 32768 + b * 2048) : (sC + l * 8192 + b * 512);
  const int* mk = blockIdx.y ? (pmask + b * 2048) : (cmask + b * 512);
  float* w = blockIdx.y ? (wP + l * 32768 + b * 2048) : (wC + l * 8192 + b * 512);
  __shared__ float red[256];
  __shared__ float e[2048];
  float m = -1e30f;
  for (int i = t; i < ntok; i += 256) m = fmaxf(m, s[i]);
  red[t] = m;
  __syncthreads();
  for (int h = 128; h; h >>= 1) { if (t < h) red[t] = fmaxf(red[t], red[t + h]); __syncthreads(); }
  const float smax = red[0];
  __syncthreads();
  float sum = 0.f;
  for (int i = t; i < ntok; i += 256) {
    const float ev = __expf(s[i] - smax) * (float)mk[i];
    e[i] = ev;
    sum += ev;
  }
  red[t] = sum;
  __syncthreads();
  for (int h = 128; h; h >>= 1) { if (t < h) red[t] += red[t + h]; __syncthreads(); }
  const float inv = 1.f / (red[0] + 1e-6f);
  for (int i = t; i < ntok; i += 256) w[i] = e[i] * inv;
}

// chunked pooling partials over all 4 layers. grid (16, 20): y<4 comp chunks, y>=4 prot
__global__ __launch_bounds__(256)
void poolpart(const float* __restrict__ wC, const float* __restrict__ wP,
              const float* __restrict__ cfeat, const float* __restrict__ pfeat,
              float* __restrict__ partC, float* __restrict__ partP) {
  const int b = blockIdx.x, y = blockIdx.y, d = threadIdx.x;
  const float* feat;
  const float* wb;
  int ls, tok0;
  float* part;
  if (y < 4) {
    feat = cfeat + (size_t)b * 512 * 256;
    wb = wC + b * 512; ls = 8192; tok0 = y * 128;
    part = partC + ((size_t)b * 4 + y) * 1024;
  } else {
    const int ch = y - 4;
    feat = pfeat + (size_t)b * 2048 * 256;
    wb = wP + b * 2048; ls = 32768; tok0 = ch * 128;
    part = partP + ((size_t)b * 16 + ch) * 1024;
  }
  float a0 = 0.f, a1 = 0.f, a2 = 0.f, a3 = 0.f;
  for (int tok = tok0; tok < tok0 + 128; tok++) {
    const float f = feat[(size_t)tok * 256 + d];
    a0 += wb[tok] * f;
    a1 += wb[ls + tok] * f;
    a2 += wb[2 * ls + tok] * f;
    a3 += wb[3 * ls + tok] * f;
  }
  part[d] = a0; part[256 + d] = a1; part[512 + d] = a2; part[768 + d] = a3;
}

// reduce partials -> pool[b][1024]. grid (16,2)
__global__ void poolreduce(const float* __restrict__ partC, const float* __restrict__ partP,
                           float* __restrict__ poolc, float* __restrict__ poolp) {
  const int b = blockIdx.x, t = threadIdx.x;
  if (blockIdx.y == 0) {
    for (int k = t; k < 1024; k += 256) {
      float s = 0.f;
      for (int ch = 0; ch < 4; ch++) s += partC[((size_t)b * 4 + ch) * 1024 + k];
      poolc[b * 1024 + k] = s;
    }
  } else {
    for (int k = t; k < 1024; k += 256) {
      float s = 0.f;
      for (int ch = 0; ch < 16; ch++) s += partP[((size_t)b * 16 + ch) * 1024 + k];
      poolp[b * 1024 + k] = s;
    }
  }
}

// out[b][n] = bias[n] + sum_k pool[b][k] * W[k][n]   (K=1024, N=256)
__global__ void final_kernel(const float* __restrict__ pool, const float* __restrict__ W,
                             const float* __restrict__ bias, float* __restrict__ outp) {
  const int b = blockIdx.x, n = threadIdx.x, q = threadIdx.y;
  __shared__ float red[4][256];
  float acc = 0.f;
  const float* p = pool + b * 1024 + q * 256;
  const float* w = W + (size_t)q * 256 * 256;
  for (int k = 0; k < 256; k++) acc += p[k] * w[(size_t)k * 256 + n];
  red[q][n] = acc;
  __syncthreads();
  if (q == 0) outp[b * 256 + n] = red[0][n] + red[1][n] + red[2][n] + red[3][n] + bias[n];
}

// ---------------------------------------------------------------------------
static inline void launch_gemm(hipStream_t s,
                               const u16* X, long long xbs, long long xls, int ldx,
                               const u16* Y, long long ybs, long long yls, int ldy,
                               void* Out, long long obs, long long ols, int obase, int ldo,
                               u16* Tout, long long tobs, long long tols, int tldo,
                               int M, int N, int K, int nz, int flags,
                               const float* bias, const int* rm, int rms,
                               const int* cm, int cms) {
  dim3 g(N / 128, M / 128, nz);
  gemm_nt<<<g, dim3(256), 0, s>>>(X, xbs, xls, ldx, Y, ybs, yls, ldy,
                                  Out, obs, ols, obase, ldo, Tout, tobs, tols, tldo,
                                  K, flags, bias, rm, rms, cm, cms);
}

extern "C" void kernel_launch(void* const* d_in, const int* in_sizes, int n_in,
                              void* d_out, int out_size, void* d_ws, size_t ws_size,
                              hipStream_t stream) {
  (void)in_sizes; (void)n_in; (void)out_size; (void)ws_size;
  enum { Bc = 16, LCc = 512, LPc = 2048, Dc = 256, Lc = 4 };

  const float* comp_feat = (const float*)d_in[0];
  const int*   comp_mask = (const int*)d_in[1];
  const float* prot_feat = (const float*)d_in[2];
  const int*   prot_mask = (const int*)d_in[3];
  const float* U     = (const float*)d_in[4];
  const float* W_p2c = (const float*)d_in[5];
  const float* b_p2c = (const float*)d_in[6];
  const float* W_c2p = (const float*)d_in[7];
  const float* b_c2p = (const float*)d_in[8];
  const float* W_hc  = (const float*)d_in[9];
  const float* b_hc  = (const float*)d_in[10];
  const float* W_hp  = (const float*)d_in[11];
  const float* b_hp  = (const float*)d_in[12];
  const float* W_ac  = (const float*)d_in[13];
  const float* b_ac  = (const float*)d_in[14];
  const float* W_ap  = (const float*)d_in[15];
  const float* b_ap  = (const float*)d_in[16];
  const float* W_cc  = (const float*)d_in[17];
  const float* b_cc  = (const float*)d_in[18];
  const float* W_cp  = (const float*)d_in[19];
  const float* b_cp  = (const float*)d_in[20];

  float* out_cf = (float*)d_out;                       // [16][256]
  float* out_pf = out_cf + Bc * Dc;                    // [16][256]
  float* CLW = out_pf + Bc * Dc;                       // [16][512][2048]
  float* PLW = CLW + (size_t)Bc * LCc * 2 * Dc * Lc;   // [16][2048][2048]

  char* wsp = (char*)d_ws;
  size_t off = 0;
  auto carve = [&](size_t bytes) -> char* {
    char* p = wsp + off;
    off += (bytes + 255) & ~(size_t)255;
    return p;
  };
  u16* cfb   = (u16*)carve((size_t)Bc * LCc * Dc * 2);
  u16* pfb   = (u16*)carve((size_t)Bc * LPc * Dc * 2);
  u16* Utb   = (u16*)carve((size_t)Lc * Dc * Dc * 2);
  u16* Wp2ct = (u16*)carve((size_t)Lc * Dc * Dc * 2);
  u16* Wc2pt = (u16*)carve((size_t)Lc * Dc * Dc * 2);
  u16* Whct  = (u16*)carve((size_t)Lc * Dc * Dc * 2);
  u16* Whpt  = (u16*)carve((size_t)Lc * Dc * Dc * 2);
  u16* CU_all   = (u16*)carve((size_t)Bc * LCc * Lc * Dc * 2);   // [b*512+c][1024]
  u16* C2Pt_all = (u16*)carve((size_t)Bc * Lc * Dc * LCc * 2);   // [b][l*256+d][512]
  u16* P2Ct_all = (u16*)carve((size_t)Bc * Lc * Dc * LPc * 2);   // [b][l*256+d][2048]
  u16* A_all  = (u16*)carve((size_t)Lc * Bc * LCc * LPc * 2);    // [l][b][c][p] 134 MB
  u16* At_all = (u16*)carve((size_t)Lc * Bc * LPc * LCc * 2);    // [l][b][p][c] 134 MB
  float* scoresC = (float*)carve((size_t)Lc * Bc * LCc * 4);
  float* scoresP = (float*)carve((size_t)Lc * Bc * LPc * 4);
  float* wCb = (float*)carve((size_t)Lc * Bc * LCc * 4);
  float* wPb = (float*)carve((size_t)Lc * Bc * LPc * 4);
  float* partC = (float*)carve((size_t)Bc * 4 * 1024 * 4);
  float* partP = (float*)carve((size_t)Bc * 16 * 1024 * 4);
  float* poolc = (float*)carve((size_t)Bc * 1024 * 4);
  float* poolp = (float*)carve((size_t)Bc * 1024 * 4);

  // --- init: bf16 features, transposed bf16 weights ---
  conv_bf16<<<dim3(Bc * LCc * Dc / 4 / 256), dim3(256), 0, stream>>>(comp_feat, cfb, Bc * LCc * Dc / 4);
  conv_bf16<<<dim3(Bc * LPc * Dc / 4 / 256), dim3(256), 0, stream>>>(prot_feat, pfb, Bc * LPc * Dc / 4);
  {
    dim3 wg(8, 8, Lc), wb(32, 8);
    wtrans<<<wg, wb, 0, stream>>>(U, Utb);
    wtrans<<<wg, wb, 0, stream>>>(W_p2c, Wp2ct);
    wtrans<<<wg, wb, 0, stream>>>(W_c2p, Wc2pt);
    wtrans<<<wg, wb, 0, stream>>>(W_hc, Whct);
    wtrans<<<wg, wb, 0, stream>>>(W_hp, Whpt);
  }

  const int LW = 2 * Dc * Lc;  // 2048

  // --- batched-over-layers weight GEMMs (N = 1024 = 4 x 256) ---
  launch_gemm(stream, cfb, 0, 0, Dc, Utb, 0, 0, Dc,
              CU_all, 0, 0, 0, Lc * Dc, nullptr, 0, 0, 0,
              Bc * LCc, Lc * Dc, Dc, 1, FLAG_NSTORE | FLAG_BF16,
              nullptr, nullptr, 0, nullptr, 0);
  launch_gemm(stream, cfb, 0, 0, Dc, Whct, 0, 0, Dc,
              CLW, 0, 0, 0, LW, nullptr, 0, 0, 0,
              Bc * LCc, Lc * Dc, Dc, 1, FLAG_NSTORE | FLAG_SPLITN | FLAG_BIAS | FLAG_TANH,
              b_hc, nullptr, 0, nullptr, 0);
  launch_gemm(stream, pfb, 0, 0, Dc, Whpt, 0, 0, Dc,
              PLW, 0, 0, 0, LW, nullptr, 0, 0, 0,
              Bc * LPc, Lc * Dc, Dc, 1, FLAG_NSTORE | FLAG_SPLITN | FLAG_BIAS | FLAG_TANH,
              b_hp, nullptr, 0, nullptr, 0);
  launch_gemm(stream, cfb, (long long)LCc * Dc, 0, Dc, Wc2pt, 0, 0, Dc,
              nullptr, 0, 0, 0, 0,
              C2Pt_all, (long long)Lc * Dc * LCc, 0, LCc,
              LCc, Lc * Dc, Dc, Bc, FLAG_TSTORE | FLAG_BIAS | FLAG_TANH,
              b_c2p, nullptr, 0, nullptr, 0);
  launch_gemm(stream, pfb, (long long)LPc * Dc, 0, Dc, Wp2ct, 0, 0, Dc,
              nullptr, 0, 0, 0, 0,
              P2Ct_all, (long long)Lc * Dc * LPc, 0, LPc,
              LPc, Lc * Dc, Dc, Bc, FLAG_TSTORE | FLAG_BIAS | FLAG_TANH,
              b_p2c, nullptr, 0, nullptr, 0);

  // --- merged-over-layers cross GEMMs (z = l*16 + b) ---
  // GEMM-1: A_all[l][b] = tanh(CU_l · pf^T)*mask, + transposed At_all
  launch_gemm(stream,
              CU_all, (long long)LCc * Lc * Dc, Dc, Lc * Dc,
              pfb, (long long)LPc * Dc, 0, Dc,
              A_all, (long long)LCc * LPc, (long long)Bc * LCc * LPc, 0, LPc,
              At_all, (long long)LPc * LCc, (long long)Bc * LPc * LCc, LCc,
              LCc, LPc, Dc, Bc * Lc,
              FLAG_NSTORE | FLAG_TSTORE | FLAG_BF16 | FLAG_TANH | FLAG_MASK,
              nullptr, comp_mask, LCc, prot_mask, LPc);
  // GEMM-2: CLW[b][c][l*512+256 + d] = A_l · tanhP2C_l   (K=2048)
  launch_gemm(stream,
              A_all, (long long)LCc * LPc, (long long)Bc * LCc * LPc, LPc,
              P2Ct_all, (long long)Lc * Dc * LPc, (long long)Dc * LPc, LPc,
              CLW, (long long)LCc * LW, 512, 256, LW, nullptr, 0, 0, 0,
              LCc, Dc, LPc, Bc * Lc, FLAG_NSTORE, nullptr, nullptr, 0, nullptr, 0);
  // GEMM-3: PLW[b][p][l*512+256 + d] = At_l · tanhC2P_l   (K=512)
  launch_gemm(stream,
              At_all, (long long)LPc * LCc, (long long)Bc * LPc * LCc, LCc,
              C2Pt_all, (long long)Lc * Dc * LCc, (long long)Dc * LCc, LCc,
              PLW, (long long)LPc * LW, 512, 256, LW, nullptr, 0, 0, 0,
              LPc, Dc, LCc, Bc * Lc, FLAG_NSTORE, nullptr, nullptr, 0, nullptr, 0);

  // --- attention scores for all layers (y = layer) ---
  scores_kernel<<<dim3(Bc * LCc / 4, Lc), dim3(256), 0, stream>>>(
      CLW, LW, W_ac, b_ac, scoresC, Bc * LCc);
  scores_kernel<<<dim3(Bc * LPc / 4, Lc), dim3(256), 0, stream>>>(
      PLW, LW, W_ap, b_ap, scoresP, Bc * LPc);

  // --- fused pooling over all layers ---
  softmax_w<<<dim3(Lc * Bc, 2), dim3(256), 0, stream>>>(scoresC, scoresP, comp_mask, prot_mask, wCb, wPb);
  poolpart<<<dim3(Bc, 20), dim3(256), 0, stream>>>(wCb, wPb, comp_feat, prot_feat, partC, partP);
  poolreduce<<<dim3(Bc, 2), dim3(256), 0, stream>>>(partC, partP, poolc, poolp);
  final_kernel<<<dim3(Bc), dim3(256, 4), 0, stream>>>(poolc, W_cc, b_cc, out_cf);
  final_kernel<<<dim3(Bc), dim3(256, 4), 0, stream>>>(poolp, W_cp, b_cp, out_pf);
}

// Round 5
// 721.490 us; speedup vs baseline: 2.1097x; 1.1743x over previous
//
#include <hip/hip_runtime.h>

typedef unsigned short u16;
typedef __attribute__((ext_vector_type(8))) short short8;
typedef __attribute__((ext_vector_type(4))) float f32x4;

#define FLAG_BIAS   1
#define FLAG_TANH   2
#define FLAG_MASK   4
#define FLAG_BF16   8
#define FLAG_NSTORE 16
#define FLAG_TSTORE 32
#define FLAG_SPLITN 64

__device__ __forceinline__ float fast_tanh(float x) {
  return 1.f - 2.f / (__expf(2.f * x) + 1.f);
}

__device__ __forceinline__ u16 f2bf(float f) {
  unsigned u = __float_as_uint(f);
  return (u16)((u + 0x7fffu + ((u >> 16) & 1u)) >> 16); // RNE
}

__device__ __forceinline__ unsigned cvtpk(float lo, float hi) {
  unsigned r;
  asm("v_cvt_pk_bf16_f32 %0, %1, %2" : "=v"(r) : "v"(lo), "v"(hi));
  return r;
}

__device__ __forceinline__ void gload_lds16(const void* g, void* l) {
  __builtin_amdgcn_global_load_lds(
      (const __attribute__((address_space(1))) unsigned int*)g,
      (__attribute__((address_space(3))) unsigned int*)l, 16, 0, 0);
}

// ---------------------------------------------------------------------------
// Generic NT GEMM: Out[r][c] = sum_k X[r][k] * Y[c][k]   (both K-contiguous)
// BM=128, BN=128 or 256, BK=32, 4 waves, mfma_f32_16x16x32_bf16, 2-phase dbuf.
// 1-D grid with XCD-chunked swizzle (consecutive work -> same XCD for L2 reuse).
// Epilogue: f32 LDS bounce, bf16 conversion on read side via v_cvt_pk_bf16_f32.
// ---------------------------------------------------------------------------
template <int BN>
__global__ __launch_bounds__(256)
void gemm_nt(const u16* __restrict__ X, long long xbs, long long xls, int ldx,
             const u16* __restrict__ Y, long long ybs, long long yls, int ldy,
             void* __restrict__ Outv, long long obs, long long ols, int obase, int ldo,
             u16* __restrict__ Tout, long long tobs, long long tols, int tldo,
             int K, int gx, int gy, int flags,
             const float* __restrict__ bias,
             const int* __restrict__ rmask, int rms,
             const int* __restrict__ cmask, int cms) {
  constexpr int NACC = BN / 32;             // accs per wave-col dim: 4 or 8
  constexpr int YB = BN * 32 * 2;           // Y bytes per buffer
  constexpr int BUFB = 8192 + YB;           // per-buffer bytes
  constexpr int BW = BN + 4;                // bounce row stride (f32)
  __shared__ __align__(16) char smem[BN == 128 ? 34816 : 49152];
  const int t = threadIdx.x;
  const int lane = t & 63, wid = t >> 6;
  const int wr = (wid >> 1) * 64, wc = (wid & 1) * (BN / 2);
  // XCD-chunked bijective swizzle (gridDim.x % 8 == 0 for all launches)
  const int lin = blockIdx.x;
  const int w = (lin & 7) * ((int)gridDim.x >> 3) + (lin >> 3);
  const int bx = w % gx;
  const int wy = w / gx;
  const int by = wy % gy;
  const int z = wy / gy;
  const int bz = z & 15, lz = z >> 4;
  const int rb = by * 128;
  const int cb = bx * BN;
  const u16* Xb = X + (size_t)bz * xbs + (size_t)lz * xls + (size_t)rb * ldx;
  const u16* Yb = Y + (size_t)bz * ybs + (size_t)lz * yls + (size_t)cb * ldy;
  const int srow = t >> 2, scol = (t & 3) * 8;
  const int r16 = lane & 15, kh = (lane >> 4) * 8;

  f32x4 acc[4][NACC];
#pragma unroll
  for (int m = 0; m < 4; m++)
#pragma unroll
    for (int n = 0; n < NACC; n++) acc[m][n] = (f32x4){0.f, 0.f, 0.f, 0.f};

  auto stage = [&](int buf, int kk) {
    char* dst = smem + buf * BUFB + t * 16;
#pragma unroll
    for (int j = 0; j < 2; j++)
      gload_lds16(Xb + (size_t)(j * 64 + srow) * ldx + kk + scol, dst + j * 4096);
#pragma unroll
    for (int j = 0; j < YB / 4096; j++)
      gload_lds16(Yb + (size_t)(j * 64 + srow) * ldy + kk + scol, dst + 8192 + j * 4096);
  };

  const int nt = K >> 5;
  stage(0, 0);
  __syncthreads();
  for (int tt = 0; tt < nt; ++tt) {
    const int cur = tt & 1;
    if (tt + 1 < nt) stage(cur ^ 1, (tt + 1) * 32);
    const u16* lx = (const u16*)(smem + cur * BUFB);
    const u16* ly = lx + 4096;
    short8 av[4], bv[NACC];
#pragma unroll
    for (int m = 0; m < 4; m++) av[m] = *(const short8*)&lx[(wr + m * 16 + r16) * 32 + kh];
#pragma unroll
    for (int n = 0; n < NACC; n++) bv[n] = *(const short8*)&ly[(wc + n * 16 + r16) * 32 + kh];
#pragma unroll
    for (int m = 0; m < 4; m++)
#pragma unroll
      for (int n = 0; n < NACC; n++)
        acc[m][n] = __builtin_amdgcn_mfma_f32_16x16x32_bf16(av[m], bv[n], acc[m][n], 0, 0, 0);
    __syncthreads();
  }

  // --- register-stage epilogue math (bias / tanh / mask), masks hoisted ---
  if (flags & (FLAG_BIAS | FLAG_TANH | FLAG_MASK)) {
    float rmv[16];
    if (flags & FLAG_MASK) {
#pragma unroll
      for (int m = 0; m < 4; m++)
#pragma unroll
        for (int j = 0; j < 4; j++)
          rmv[m * 4 + j] =
              (float)rmask[(size_t)bz * rms + rb + wr + m * 16 + ((lane >> 4) << 2) + j];
    }
#pragma unroll
    for (int n = 0; n < NACC; n++) {
      const int c = cb + wc + n * 16 + r16;
      const float bcol = (flags & FLAG_BIAS) ? bias[c] : 0.f;
      const float cmv = (flags & FLAG_MASK) ? (float)cmask[(size_t)bz * cms + c] : 1.f;
#pragma unroll
      for (int m = 0; m < 4; m++) {
#pragma unroll
        for (int j = 0; j < 4; j++) {
          float v = acc[m][n][j] + bcol;
          if (flags & FLAG_TANH) v = fast_tanh(v);
          if (flags & FLAG_MASK) v *= cmv * rmv[m * 4 + j];
          acc[m][n][j] = v;
        }
      }
    }
  }

  const size_t ocol = (flags & FLAG_SPLITN) ? (size_t)((cb >> 8) * 512 + (cb & 255))
                                            : (size_t)obase + (size_t)lz * ols + cb;

  if (flags & FLAG_NSTORE) {
    // 4 passes over m; bounce 32 rows x BN f32
#pragma unroll
    for (int m = 0; m < 4; m++) {
      __syncthreads();
      float* bb = (float*)smem;
#pragma unroll
      for (int n = 0; n < NACC; n++)
#pragma unroll
        for (int j = 0; j < 4; j++)
          bb[((wid >> 1) * 16 + ((lane >> 4) << 2) + j) * BW + wc + n * 16 + r16] =
              acc[m][n][j];
      __syncthreads();
      const int lr = t >> 3;                 // 32 rows x 8 threads
      const int c0 = (t & 7) * (BN / 8);
      const int g = rb + (lr >> 4) * 64 + m * 16 + (lr & 15);
      const float4* src = (const float4*)&bb[lr * BW + c0];
      if (flags & FLAG_BF16) {
        u16* op = (u16*)Outv + (size_t)bz * obs + (size_t)g * ldo + ocol + c0;
#pragma unroll
        for (int q = 0; q < BN / 64; q++) {
          const float4 f0 = src[2 * q], f1 = src[2 * q + 1];
          uint4 u;
          u.x = cvtpk(f0.x, f0.y); u.y = cvtpk(f0.z, f0.w);
          u.z = cvtpk(f1.x, f1.y); u.w = cvtpk(f1.z, f1.w);
          ((uint4*)op)[q] = u;
        }
      } else {
        float* op = (float*)Outv + (size_t)bz * obs + (size_t)g * ldo + ocol + c0;
#pragma unroll
        for (int q = 0; q < BN / 32; q++) ((float4*)op)[q] = src[q];
      }
    }
  }

  if constexpr (BN == 128) {
    if (flags & FLAG_TSTORE) {
      // 2 passes over n-halves; transposed bounce 64 cols x (128+4) f32
#pragma unroll
      for (int np = 0; np < 2; np++) {
        __syncthreads();
        float* bb = (float*)smem;
#pragma unroll
        for (int q = 0; q < 2; q++) {
          const int n = np * 2 + q;
#pragma unroll
          for (int m = 0; m < 4; m++)
#pragma unroll
            for (int j = 0; j < 4; j++)
              bb[((wid & 1) * 32 + q * 16 + r16) * 132 + wr + m * 16 + ((lane >> 4) << 2) + j] =
                  acc[m][n][j];
        }
        __syncthreads();
        const int lc = t >> 2, r0 = (t & 3) * 32;  // 64 cols x 4 threads x 32 rows
        const int colg = cb + (lc >> 5) * 64 + (np * 2 + ((lc >> 4) & 1)) * 16 + (lc & 15);
        const float4* src = (const float4*)&bb[lc * 132 + r0];
        u16* op = Tout + (size_t)lz * tols + (size_t)bz * tobs + (size_t)colg * tldo + rb + r0;
#pragma unroll
        for (int q = 0; q < 4; q++) {
          const float4 f0 = src[2 * q], f1 = src[2 * q + 1];
          uint4 u;
          u.x = cvtpk(f0.x, f0.y); u.y = cvtpk(f0.z, f0.w);
          u.z = cvtpk(f1.x, f1.y); u.w = cvtpk(f1.z, f1.w);
          ((uint4*)op)[q] = u;
        }
      }
    }
  }
}

// 5 weight tensors f32 [L][256][256] -> bf16 transposed; z = which*4 + l
__global__ void wtrans5(const float* __restrict__ iU, const float* __restrict__ iP2C,
                        const float* __restrict__ iC2P, const float* __restrict__ iHC,
                        const float* __restrict__ iHP,
                        u16* __restrict__ oU, u16* __restrict__ oP2C,
                        u16* __restrict__ oC2P, u16* __restrict__ oHC,
                        u16* __restrict__ oHP) {
  __shared__ float tl[32][33];
  const int which = blockIdx.z >> 2, l = blockIdx.z & 3;
  const float* in;
  u16* out;
  switch (which) {
    case 0: in = iU;   out = oU;   break;
    case 1: in = iP2C; out = oP2C; break;
    case 2: in = iC2P; out = oC2P; break;
    case 3: in = iHC;  out = oHC;  break;
    default: in = iHP; out = oHP;  break;
  }
  const size_t bo = (size_t)l * 256 * 256;
  const int c0 = blockIdx.x * 32, r0 = blockIdx.y * 32;
  for (int i = threadIdx.y; i < 32; i += 8)
    tl[i][threadIdx.x] = in[bo + (size_t)(r0 + i) * 256 + c0 + threadIdx.x];
  __syncthreads();
  for (int i = threadIdx.y; i < 32; i += 8)
    out[bo + (size_t)(c0 + i) * 256 + r0 + threadIdx.x] = f2bf(tl[threadIdx.x][i]);
}

__global__ void conv_bf16(const float* __restrict__ in, u16* __restrict__ out, int n4) {
  const int i = blockIdx.x * 256 + threadIdx.x;
  if (i >= n4) return;
  const float4 v = ((const float4*)in)[i];
  ushort4 o;
  o.x = f2bf(v.x); o.y = f2bf(v.y); o.z = f2bf(v.z); o.w = f2bf(v.w);
  ((ushort4*)out)[i] = o;
}

// wave per token, layer = blockIdx.y: score = dot(comb[tok, l*512 : l*512+512], wvec_l)
__global__ void scores_kernel(const float* __restrict__ comb, int tokstride,
                              const float* __restrict__ wvec, const float* __restrict__ bsc,
                              float* __restrict__ outp, int ntoks) {
  const int l = blockIdx.y;
  const int lane = threadIdx.x & 63, wid = threadIdx.x >> 6;
  const int tok = blockIdx.x * 4 + wid;
  const float* p = comb + (size_t)tok * tokstride + (size_t)l * 512 + lane * 8;
  const float4 a = *(const float4*)p, b = *(const float4*)(p + 4);
  const float* wp = wvec + (size_t)l * 512 + lane * 8;
  const float4 wa = *(const float4*)wp, wb = *(const float4*)(wp + 4);
  float s = a.x * wa.x + a.y * wa.y + a.z * wa.z + a.w * wa.w +
            b.x * wb.x + b.y * wb.y + b.z * wb.z + b.w * wb.w;
#pragma unroll
  for (int off = 32; off; off >>= 1) s += __shfl_down(s, off);
  if (lane == 0) outp[(size_t)l * ntoks + tok] = s + bsc[l];
}

// masked softmax -> normalized weights. grid(64, 2): x = l*16+b, y: 0=comp 1=prot
__global__ __launch_bounds__(256)
void softmax_w(const float* __restrict__ sC, const float* __restrict__ sP,
               const int* __restrict__ cmask, const int* __restrict__ pmask,
               float* __restrict__ wC, float* __restrict__ wP) {
  const int l = blockIdx.x >> 4, b = blockIdx.x & 15, t = threadIdx.x;
  const int ntok = blockIdx.y ? 2048 : 512;
  const float* s = blockIdx.y ? (sP + l * 32768 + b * 2048) : (sC + l * 8192 + b * 512);
  const int* mk = blockIdx.y ? (pmask + b * 2048) : (cmask + b * 512);
  float* w = blockIdx.y ? (wP + l * 32768 + b * 2048) : (wC + l * 8192 + b * 512);
  __shared__ float red[256];
  __shared__ float e[2048];
  float m = -1e30f;
  for (int i = t; i < ntok; i += 256) m = fmaxf(m, s[i]);
  red[t] = m;
  __syncthreads();
  for (int h = 128; h; h >>= 1) { if (t < h) red[t] = fmaxf(red[t], red[t + h]); __syncthreads(); }
  const float smax = red[0];
  __syncthreads();
  float sum = 0.f;
  for (int i = t; i < ntok; i += 256) {
    const float ev = __expf(s[i] - smax) * (float)mk[i];
    e[i] = ev;
    sum += ev;
  }
  red[t] = sum;
  __syncthreads();
  for (int h = 128; h; h >>= 1) { if (t < h) red[t] += red[t + h]; __syncthreads(); }
  const float inv = 1.f / (red[0] + 1e-6f);
  for (int i = t; i < ntok; i += 256) w[i] = e[i] * inv;
}

// chunked pooling partials over all 4 layers. grid (16, 20): y<4 comp chunks, y>=4 prot
__global__ __launch_bounds__(256)
void poolpart(const float* __restrict__ wC, const float* __restrict__ wP,
              const float* __restrict__ cfeat, const float* __restrict__ pfeat,
              float* __restrict__ partC, float* __restrict__ partP) {
  const int b = blockIdx.x, y = blockIdx.y, d = threadIdx.x;
  const float* feat;
  const float* wb;
  int ls, tok0;
  float* part;
  if (y < 4) {
    feat = cfeat + (size_t)b * 512 * 256;
    wb = wC + b * 512; ls = 8192; tok0 = y * 128;
    part = partC + ((size_t)b * 4 + y) * 1024;
  } else {
    const int ch = y - 4;
    feat = pfeat + (size_t)b * 2048 * 256;
    wb = wP + b * 2048; ls = 32768; tok0 = ch * 128;
    part = partP + ((size_t)b * 16 + ch) * 1024;
  }
  float a0 = 0.f, a1 = 0.f, a2 = 0.f, a3 = 0.f;
  for (int tok = tok0; tok < tok0 + 128; tok++) {
    const float f = feat[(size_t)tok * 256 + d];
    a0 += wb[tok] * f;
    a1 += wb[ls + tok] * f;
    a2 += wb[2 * ls + tok] * f;
    a3 += wb[3 * ls + tok] * f;
  }
  part[d] = a0; part[256 + d] = a1; part[512 + d] = a2; part[768 + d] = a3;
}

// reduce partials -> pool[b][1024]. grid (16,2)
__global__ void poolreduce(const float* __restrict__ partC, const float* __restrict__ partP,
                           float* __restrict__ poolc, float* __restrict__ poolp) {
  const int b = blockIdx.x, t = threadIdx.x;
  if (blockIdx.y == 0) {
    for (int k = t; k < 1024; k += 256) {
      float s = 0.f;
      for (int ch = 0; ch < 4; ch++) s += partC[((size_t)b * 4 + ch) * 1024 + k];
      poolc[b * 1024 + k] = s;
    }
  } else {
    for (int k = t; k < 1024; k += 256) {
      float s = 0.f;
      for (int ch = 0; ch < 16; ch++) s += partP[((size_t)b * 16 + ch) * 1024 + k];
      poolp[b * 1024 + k] = s;
    }
  }
}

// out[b][n] = bias[n] + sum_k pool[b][k] * W[k][n]   (K=1024, N=256)
__global__ void final_kernel(const float* __restrict__ pool, const float* __restrict__ W,
                             const float* __restrict__ bias, float* __restrict__ outp) {
  const int b = blockIdx.x, n = threadIdx.x, q = threadIdx.y;
  __shared__ float red[4][256];
  float acc = 0.f;
  const float* p = pool + b * 1024 + q * 256;
  const float* w = W + (size_t)q * 256 * 256;
  for (int k = 0; k < 256; k++) acc += p[k] * w[(size_t)k * 256 + n];
  red[q][n] = acc;
  __syncthreads();
  if (q == 0) outp[b * 256 + n] = red[0][n] + red[1][n] + red[2][n] + red[3][n] + bias[n];
}

// ---------------------------------------------------------------------------
static inline void launch_gemm(hipStream_t s, int BN,
                               const u16* X, long long xbs, long long xls, int ldx,
                               const u16* Y, long long ybs, long long yls, int ldy,
                               void* Out, long long obs, long long ols, int obase, int ldo,
                               u16* Tout, long long tobs, long long tols, int tldo,
                               int M, int N, int K, int nz, int flags,
                               const float* bias, const int* rm, int rms,
                               const int* cm, int cms) {
  const int gx = N / BN, gy = M / 128;
  const int nb = gx * gy * nz;
  if (BN == 128)
    gemm_nt<128><<<dim3(nb), dim3(256), 0, s>>>(X, xbs, xls, ldx, Y, ybs, yls, ldy,
                                                Out, obs, ols, obase, ldo,
                                                Tout, tobs, tols, tldo,
                                                K, gx, gy, flags, bias, rm, rms, cm, cms);
  else
    gemm_nt<256><<<dim3(nb), dim3(256), 0, s>>>(X, xbs, xls, ldx, Y, ybs, yls, ldy,
                                                Out, obs, ols, obase, ldo,
                                                Tout, tobs, tols, tldo,
                                                K, gx, gy, flags, bias, rm, rms, cm, cms);
}

extern "C" void kernel_launch(void* const* d_in, const int* in_sizes, int n_in,
                              void* d_out, int out_size, void* d_ws, size_t ws_size,
                              hipStream_t stream) {
  (void)in_sizes; (void)n_in; (void)out_size; (void)ws_size;
  enum { Bc = 16, LCc = 512, LPc = 2048, Dc = 256, Lc = 4 };

  const float* comp_feat = (const float*)d_in[0];
  const int*   comp_mask = (const int*)d_in[1];
  const float* prot_feat = (const float*)d_in[2];
  const int*   prot_mask = (const int*)d_in[3];
  const float* U     = (const float*)d_in[4];
  const float* W_p2c = (const float*)d_in[5];
  const float* b_p2c = (const float*)d_in[6];
  const float* W_c2p = (const float*)d_in[7];
  const float* b_c2p = (const float*)d_in[8];
  const float* W_hc  = (const float*)d_in[9];
  const float* b_hc  = (const float*)d_in[10];
  const float* W_hp  = (const float*)d_in[11];
  const float* b_hp  = (const float*)d_in[12];
  const float* W_ac  = (const float*)d_in[13];
  const float* b_ac  = (const float*)d_in[14];
  const float* W_ap  = (const float*)d_in[15];
  const float* b_ap  = (const float*)d_in[16];
  const float* W_cc  = (const float*)d_in[17];
  const float* b_cc  = (const float*)d_in[18];
  const float* W_cp  = (const float*)d_in[19];
  const float* b_cp  = (const float*)d_in[20];

  float* out_cf = (float*)d_out;                       // [16][256]
  float* out_pf = out_cf + Bc * Dc;                    // [16][256]
  float* CLW = out_pf + Bc * Dc;                       // [16][512][2048]
  float* PLW = CLW + (size_t)Bc * LCc * 2 * Dc * Lc;   // [16][2048][2048]

  char* wsp = (char*)d_ws;
  size_t off = 0;
  auto carve = [&](size_t bytes) -> char* {
    char* p = wsp + off;
    off += (bytes + 255) & ~(size_t)255;
    return p;
  };
  u16* cfb   = (u16*)carve((size_t)Bc * LCc * Dc * 2);
  u16* pfb   = (u16*)carve((size_t)Bc * LPc * Dc * 2);
  u16* Utb   = (u16*)carve((size_t)Lc * Dc * Dc * 2);
  u16* Wp2ct = (u16*)carve((size_t)Lc * Dc * Dc * 2);
  u16* Wc2pt = (u16*)carve((size_t)Lc * Dc * Dc * 2);
  u16* Whct  = (u16*)carve((size_t)Lc * Dc * Dc * 2);
  u16* Whpt  = (u16*)carve((size_t)Lc * Dc * Dc * 2);
  u16* CU_all   = (u16*)carve((size_t)Bc * LCc * Lc * Dc * 2);   // [b*512+c][1024]
  u16* C2Pt_all = (u16*)carve((size_t)Bc * Lc * Dc * LCc * 2);   // [b][l*256+d][512]
  u16* P2Ct_all = (u16*)carve((size_t)Bc * Lc * Dc * LPc * 2);   // [b][l*256+d][2048]
  u16* A_all  = (u16*)carve((size_t)Lc * Bc * LCc * LPc * 2);    // [l][b][c][p]
  u16* At_all = (u16*)carve((size_t)Lc * Bc * LPc * LCc * 2);    // [l][b][p][c]
  float* scoresC = (float*)carve((size_t)Lc * Bc * LCc * 4);
  float* scoresP = (float*)carve((size_t)Lc * Bc * LPc * 4);
  float* wCb = (float*)carve((size_t)Lc * Bc * LCc * 4);
  float* wPb = (float*)carve((size_t)Lc * Bc * LPc * 4);
  float* partC = (float*)carve((size_t)Bc * 4 * 1024 * 4);
  float* partP = (float*)carve((size_t)Bc * 16 * 1024 * 4);
  float* poolc = (float*)carve((size_t)Bc * 1024 * 4);
  float* poolp = (float*)carve((size_t)Bc * 1024 * 4);

  // --- init: bf16 features, transposed bf16 weights (merged) ---
  conv_bf16<<<dim3(Bc * LCc * Dc / 4 / 256), dim3(256), 0, stream>>>(comp_feat, cfb, Bc * LCc * Dc / 4);
  conv_bf16<<<dim3(Bc * LPc * Dc / 4 / 256), dim3(256), 0, stream>>>(prot_feat, pfb, Bc * LPc * Dc / 4);
  wtrans5<<<dim3(8, 8, 20), dim3(32, 8), 0, stream>>>(U, W_p2c, W_c2p, W_hc, W_hp,
                                                      Utb, Wp2ct, Wc2pt, Whct, Whpt);

  const int LW = 2 * Dc * Lc;  // 2048

  // --- batched-over-layers weight GEMMs (N = 1024 = 4 x 256) ---
  launch_gemm(stream, 128, cfb, 0, 0, Dc, Utb, 0, 0, Dc,
              CU_all, 0, 0, 0, Lc * Dc, nullptr, 0, 0, 0,
              Bc * LCc, Lc * Dc, Dc, 1, FLAG_NSTORE | FLAG_BF16,
              nullptr, nullptr, 0, nullptr, 0);
  launch_gemm(stream, 128, cfb, 0, 0, Dc, Whct, 0, 0, Dc,
              CLW, 0, 0, 0, LW, nullptr, 0, 0, 0,
              Bc * LCc, Lc * Dc, Dc, 1, FLAG_NSTORE | FLAG_SPLITN | FLAG_BIAS | FLAG_TANH,
              b_hc, nullptr, 0, nullptr, 0);
  launch_gemm(stream, 128, pfb, 0, 0, Dc, Whpt, 0, 0, Dc,
              PLW, 0, 0, 0, LW, nullptr, 0, 0, 0,
              Bc * LPc, Lc * Dc, Dc, 1, FLAG_NSTORE | FLAG_SPLITN | FLAG_BIAS | FLAG_TANH,
              b_hp, nullptr, 0, nullptr, 0);
  launch_gemm(stream, 128, cfb, (long long)LCc * Dc, 0, Dc, Wc2pt, 0, 0, Dc,
              nullptr, 0, 0, 0, 0,
              C2Pt_all, (long long)Lc * Dc * LCc, 0, LCc,
              LCc, Lc * Dc, Dc, Bc, FLAG_TSTORE | FLAG_BIAS | FLAG_TANH,
              b_c2p, nullptr, 0, nullptr, 0);
  launch_gemm(stream, 128, pfb, (long long)LPc * Dc, 0, Dc, Wp2ct, 0, 0, Dc,
              nullptr, 0, 0, 0, 0,
              P2Ct_all, (long long)Lc * Dc * LPc, 0, LPc,
              LPc, Lc * Dc, Dc, Bc, FLAG_TSTORE | FLAG_BIAS | FLAG_TANH,
              b_p2c, nullptr, 0, nullptr, 0);

  // --- merged-over-layers cross GEMMs (z = l*16 + b) ---
  // GEMM-1: A_all[l][b] = tanh(CU_l · pf^T)*mask, + transposed At_all
  launch_gemm(stream, 128,
              CU_all, (long long)LCc * Lc * Dc, Dc, Lc * Dc,
              pfb, (long long)LPc * Dc, 0, Dc,
              A_all, (long long)LCc * LPc, (long long)Bc * LCc * LPc, 0, LPc,
              At_all, (long long)LPc * LCc, (long long)Bc * LPc * LCc, LCc,
              LCc, LPc, Dc, Bc * Lc,
              FLAG_NSTORE | FLAG_TSTORE | FLAG_BF16 | FLAG_TANH | FLAG_MASK,
              nullptr, comp_mask, LCc, prot_mask, LPc);
  // GEMM-2: CLW[b][c][l*512+256 + d] = A_l · tanhP2C_l   (K=2048), BN=256
  launch_gemm(stream, 256,
              A_all, (long long)LCc * LPc, (long long)Bc * LCc * LPc, LPc,
              P2Ct_all, (long long)Lc * Dc * LPc, (long long)Dc * LPc, LPc,
              CLW, (long long)LCc * LW, 512, 256, LW, nullptr, 0, 0, 0,
              LCc, Dc, LPc, Bc * Lc, FLAG_NSTORE, nullptr, nullptr, 0, nullptr, 0);
  // GEMM-3: PLW[b][p][l*512+256 + d] = At_l · tanhC2P_l   (K=512), BN=256
  launch_gemm(stream, 256,
              At_all, (long long)LPc * LCc, (long long)Bc * LPc * LCc, LCc,
              C2Pt_all, (long long)Lc * Dc * LCc, (long long)Dc * LCc, LCc,
              PLW, (long long)LPc * LW, 512, 256, LW, nullptr, 0, 0, 0,
              LPc, Dc, LCc, Bc * Lc, FLAG_NSTORE, nullptr, nullptr, 0, nullptr, 0);

  // --- attention scores for all layers (y = layer) ---
  scores_kernel<<<dim3(Bc * LCc / 4, Lc), dim3(256), 0, stream>>>(
      CLW, LW, W_ac, b_ac, scoresC, Bc * LCc);
  scores_kernel<<<dim3(Bc * LPc / 4, Lc), dim3(256), 0, stream>>>(
      PLW, LW, W_ap, b_ap, scoresP, Bc * LPc);

  // --- fused pooling over all layers ---
  softmax_w<<<dim3(Lc * Bc, 2), dim3(256), 0, stream>>>(scoresC, scoresP, comp_mask, prot_mask, wCb, wPb);
  poolpart<<<dim3(Bc, 20), dim3(256), 0, stream>>>(wCb, wPb, comp_feat, prot_feat, partC, partP);
  poolreduce<<<dim3(Bc, 2), dim3(256), 0, stream>>>(partC, partP, poolc, poolp);
  final_kernel<<<dim3(Bc), dim3(256, 4), 0, stream>>>(poolc, W_cc, b_cc, out_cf);
  final_kernel<<<dim3(Bc), dim3(256, 4), 0, stream>>>(poolp, W_cp, b_cp, out_pf);
}